// Round 9
// baseline (146.163 us; speedup 1.0000x reference)
//
#include <hip/hip_runtime.h>
#include <hip/hip_bf16.h>

typedef float f32x4 __attribute__((ext_vector_type(4)));
typedef __bf16 bf16x8 __attribute__((ext_vector_type(8)));

union Frag { unsigned short h[8]; unsigned int u[4]; uint4 u4; bf16x8 b; };

__device__ __forceinline__ unsigned short f2bs(float f){
  __hip_bfloat16 v = __float2bfloat16(f);
  return __builtin_bit_cast(unsigned short, v);
}
// 1-instruction bf16 pair pack (RNE)
__device__ __forceinline__ unsigned int pk2(float a, float b){
  unsigned int r;
  asm("v_cvt_pk_bf16_f32 %0, %1, %2" : "=v"(r) : "v"(a), "v"(b));
  return r;
}
__device__ __forceinline__ Frag packF(f32x4 a, f32x4 b){
  Frag f;
  f.u[0] = pk2(a[0], a[1]); f.u[1] = pk2(a[2], a[3]);
  f.u[2] = pk2(b[0], b[1]); f.u[3] = pk2(b[2], b[3]);
  return f;
}
__device__ __forceinline__ f32x4 relu4(f32x4 v){
  f32x4 r;
  #pragma unroll
  for (int j = 0; j < 4; ++j) r[j] = fmaxf(v[j], 0.f);
  return r;
}
__device__ __forceinline__ float sigmoid_fast(float x){
  return __builtin_amdgcn_rcpf(1.f + __expf(-x));
}

// ---------------------------------------------------------------------------
// Prep: weight matrices -> MFMA A-frag order bf16 (ws[0..4095] uint4), plus
// r2e's 5 rows pre-packed as B-frag pairs (ws[4096..4735]).
// A-frag element (h,j): W[16*m + (lane&15)][32*s + 16*h + 4*(lane>>4) + j]
// ---------------------------------------------------------------------------
__global__ void prep_weights(const float* __restrict__ w1, const float* __restrict__ w2,
                             const float* __restrict__ mu, const float* __restrict__ a1,
                             const float* __restrict__ a2, const float* __restrict__ r2e,
                             uint4* __restrict__ ws){
  const int f = blockIdx.x;
  const int l = threadIdx.x;
  Frag fr;
  if (f < 64){
    const float* W; int m, s, K;
    if (f < 16)      { W = w1; m = f >> 2;        s = f & 3;        K = 128; }
    else if (f < 24) { W = w2; m = (f - 16) >> 1; s = (f - 16) & 1; K = 64;  }
    else if (f < 40) { W = mu; m = (f - 24) >> 2; s = (f - 24) & 3; K = 128; }
    else if (f < 56) { W = a1; m = (f - 40) >> 2; s = (f - 40) & 3; K = 128; }
    else             { W = a2; m = (f - 56) >> 1; s = (f - 56) & 1; K = 64;  }
    const int row = 16 * m + (l & 15);
    const int k0  = 32 * s + 4 * (l >> 4);
    #pragma unroll
    for (int h = 0; h < 2; ++h)
      #pragma unroll
      for (int j = 0; j < 4; ++j)
        fr.h[4*h + j] = f2bs(W[row * K + k0 + 16*h + j]);
    ws[f * 64 + l] = fr.u4;
  } else {
    const int f2 = f - 64;            // 0..9
    const int R = f2 >> 1, sp = f2 & 1;
    const int g = (l >> 4) & 3;
    #pragma unroll
    for (int h = 0; h < 2; ++h)
      #pragma unroll
      for (int j = 0; j < 4; ++j)
        fr.h[4*h + j] = f2bs(r2e[R * 64 + sp * 32 + 16*h + 4*g + j]);
    ws[4096 + f2 * 64 + l] = fr.u4;
  }
}

// ---------------------------------------------------------------------------
// Main: grid 512 x 256thr, wave w owns node n = b*4+w end-to-end, dual-chunk
// (2x ILP) pipeline per wave (round-6 structure, known-good).
// Round-9 delta: WEIGHTS STAY IN GLOBAL/L2. Round 5 measured the weight path
// LDS-vs-L2 as perf-neutral (78.9 vs 77.8us); the 64KB LDS table was capping
// occupancy at 2 blocks/CU. LDS now ~12KB (bias + r2e frags) so blocks/CU is
// register-limited -> expect 3-4 waves/SIMD with round 6's lean allocation.
// Also: per-lane deferred es-accumulate (round-7-verified numerics) removes
// 8 dependent ds_swizzles per iteration.
// NOTE: no min-waves launch_bounds arg (round 3: forced cap => ~1GB spill).
// ---------------------------------------------------------------------------
__global__ __launch_bounds__(256)
void uv_agg_main(const int* __restrict__ nodes, const int* __restrict__ huv,
                 const int* __restrict__ hr, const float* __restrict__ u2e,
                 const float* __restrict__ v2e,
                 const float* __restrict__ b1g, const float* __restrict__ b2g,
                 const float* __restrict__ bmg, const float* __restrict__ ba1g,
                 const float* __restrict__ ba2g, const float* __restrict__ a3g,
                 const uint4* __restrict__ wsfrag, float* __restrict__ out){
  __shared__ float bias[384];
  __shared__ uint4 rlds[640];

  const int tid  = threadIdx.x;
  const int lane = tid & 63;
  const int wave = tid >> 6;
  const int g    = lane >> 4;
  const int r16  = lane & 15;
  const int n    = blockIdx.x * 4 + wave;

  // stage r2e frags + biases into LDS (weights remain global/L2-resident)
  for (int i = tid; i < 640; i += 256)  rlds[i] = wsfrag[4096 + i];
  if (tid < 384){
    const int w = tid >> 6, d = tid & 63;
    const float* src = (w==0)?b1g:(w==1)?b2g:(w==2)?bmg:(w==3)?ba1g:(w==4)?ba2g:a3g;
    bias[tid] = src[d];
  }
  __syncthreads();

  const uint4* wl = wsfrag + lane;               // weight frags from L2
  const f32x4* bl = (const f32x4*)bias + g;
  const unsigned char* rbase = (const unsigned char*)rlds + lane * 16;
  const int* hu  = huv + n * 200;
  const int* hrw = hr  + n * 200;

  // per-node q = v2e[nodes[n]]
  const int item = nodes[n];
  f32x4 qv[4];
  #pragma unroll
  for (int m = 0; m < 4; ++m)
    qv[m] = *(const f32x4*)(v2e + (size_t)item * 64 + 16*m + 4*g);
  Frag qf[2];
  qf[0] = packF(qv[0], qv[1]); qf[1] = packF(qv[2], qv[3]);

  float swl = 0.f;                 // per-lane exp-sum (reduced in finale)
  f32x4 accw[4];
  #pragma unroll
  for (int m = 0; m < 4; ++m) accw[m] = (f32x4)(0.f);

  // initial gather: tiles 0 and 1
  int irA, irB;
  f32x4 urA[4], urB[4];
  {
    const int iuA = hu[r16];      irA = hrw[r16];
    const int iuB = hu[16 + r16]; irB = hrw[16 + r16];
    const f32x4* ua = (const f32x4*)(u2e + (size_t)iuA * 64);
    const f32x4* ub = (const f32x4*)(u2e + (size_t)iuB * 64);
    #pragma unroll
    for (int s = 0; s < 4; ++s){ urA[s] = ua[4*s + g]; urB[s] = ub[4*s + g]; }
  }

  for (int it = 0; it < 7; ++it){
    Frag b0A[2], b0B[2];
    b0A[0] = packF(urA[0], urA[1]); b0A[1] = packF(urA[2], urA[3]);
    b0B[0] = packF(urB[0], urB[1]); b0B[1] = packF(urB[2], urB[3]);
    const int ircA = irA, ircB = irB;
    const bool vA = (32*it + r16) < 200;
    const bool vB = (32*it + 16 + r16) < 200;

    // prefetch next pair (independent of this iteration's chains)
    if (it < 6){
      const int base = 32*it + 32;
      const int kA = min(base + r16, 199);
      const int kB = min(base + 16 + r16, 199);
      const int iuA = hu[kA]; irA = hrw[kA];
      const int iuB = hu[kB]; irB = hrw[kB];
      const f32x4* ua = (const f32x4*)(u2e + (size_t)iuA * 64);
      const f32x4* ub = (const f32x4*)(u2e + (size_t)iuB * 64);
      #pragma unroll
      for (int s = 0; s < 4; ++s){ urA[s] = ua[4*s + g]; urB[s] = ub[4*s + g]; }
    }

    // S1: X = relu(W1 @ concat(e_uv, e_r) + b1)   [two chunks interleaved]
    f32x4 XA[4], XB[4];
    #pragma unroll
    for (int m = 0; m < 4; ++m){
      const f32x4 bi = bl[0*16 + 4*m];
      f32x4 aA = bi, aB = bi;
      #pragma unroll
      for (int s = 0; s < 4; ++s){
        Frag w; w.u4 = wl[(m*4 + s) * 64];
        Frag eA, eB;
        if (s < 2){ eA = b0A[s]; eB = b0B[s]; }
        else {
          eA.u4 = *(const uint4*)(rbase + (size_t)(ircA*2 + (s-2)) * 1024);
          eB.u4 = *(const uint4*)(rbase + (size_t)(ircB*2 + (s-2)) * 1024);
        }
        aA = __builtin_amdgcn_mfma_f32_16x16x32_bf16(w.b, eA.b, aA, 0, 0, 0);
        aB = __builtin_amdgcn_mfma_f32_16x16x32_bf16(w.b, eB.b, aB, 0, 0, 0);
      }
      XA[m] = relu4(aA); XB[m] = relu4(aB);
    }
    Frag bxA[2], bxB[2];
    bxA[0] = packF(XA[0], XA[1]); bxA[1] = packF(XA[2], XA[3]);
    bxB[0] = packF(XB[0], XB[1]); bxB[1] = packF(XB[2], XB[3]);

    // S2: O = relu(W2 @ X + b2)
    f32x4 OA[4], OB[4];
    #pragma unroll
    for (int m = 0; m < 4; ++m){
      const f32x4 bi = bl[1*16 + 4*m];
      f32x4 aA = bi, aB = bi;
      #pragma unroll
      for (int s = 0; s < 2; ++s){
        Frag w; w.u4 = wl[(16 + m*2 + s) * 64];
        aA = __builtin_amdgcn_mfma_f32_16x16x32_bf16(w.b, bxA[s].b, aA, 0, 0, 0);
        aB = __builtin_amdgcn_mfma_f32_16x16x32_bf16(w.b, bxB[s].b, aB, 0, 0, 0);
      }
      OA[m] = relu4(aA); OB[m] = relu4(aB);
    }
    Frag boA[2], boB[2];
    boA[0] = packF(OA[0], OA[1]); boA[1] = packF(OA[2], OA[3]);
    boB[0] = packF(OB[0], OB[1]); boB[1] = packF(OB[2], OB[3]);

    // S3: gate = sigmoid(MU @ concat(O,q) + mu_b); OG = q + gate*(O-q)
    f32x4 OGA[4], OGB[4];
    #pragma unroll
    for (int m = 0; m < 4; ++m){
      const f32x4 bi = bl[2*16 + 4*m];
      f32x4 aA = bi, aB = bi;
      #pragma unroll
      for (int s = 0; s < 4; ++s){
        Frag w; w.u4 = wl[(24 + m*4 + s) * 64];
        const bf16x8 eA = (s < 2) ? boA[s].b : qf[s-2].b;
        const bf16x8 eB = (s < 2) ? boB[s].b : qf[s-2].b;
        aA = __builtin_amdgcn_mfma_f32_16x16x32_bf16(w.b, eA, aA, 0, 0, 0);
        aB = __builtin_amdgcn_mfma_f32_16x16x32_bf16(w.b, eB, aB, 0, 0, 0);
      }
      #pragma unroll
      for (int j = 0; j < 4; ++j){
        const float gA = sigmoid_fast(aA[j]);
        const float gB = sigmoid_fast(aB[j]);
        OGA[m][j] = fmaf(gA, OA[m][j] - qv[m][j], qv[m][j]);
        OGB[m][j] = fmaf(gB, OB[m][j] - qv[m][j], qv[m][j]);
      }
    }
    Frag bgA[2], bgB[2];
    bgA[0] = packF(OGA[0], OGA[1]); bgA[1] = packF(OGA[2], OGA[3]);
    bgB[0] = packF(OGB[0], OGB[1]); bgB[1] = packF(OGB[2], OGB[3]);

    // S4: A1 = relu(ATT1 @ concat(OG,q) + att1_b)
    f32x4 A1A[4], A1B[4];
    #pragma unroll
    for (int m = 0; m < 4; ++m){
      const f32x4 bi = bl[3*16 + 4*m];
      f32x4 aA = bi, aB = bi;
      #pragma unroll
      for (int s = 0; s < 4; ++s){
        Frag w; w.u4 = wl[(40 + m*4 + s) * 64];
        const bf16x8 eA = (s < 2) ? bgA[s].b : qf[s-2].b;
        const bf16x8 eB = (s < 2) ? bgB[s].b : qf[s-2].b;
        aA = __builtin_amdgcn_mfma_f32_16x16x32_bf16(w.b, eA, aA, 0, 0, 0);
        aB = __builtin_amdgcn_mfma_f32_16x16x32_bf16(w.b, eB, aB, 0, 0, 0);
      }
      A1A[m] = relu4(aA); A1B[m] = relu4(aB);
    }
    Frag b4A[2], b4B[2];
    b4A[0] = packF(A1A[0], A1A[1]); b4A[1] = packF(A1A[2], A1A[3]);
    b4B[0] = packF(A1B[0], A1B[1]); b4B[1] = packF(A1B[2], A1B[3]);

    // S5: A2 = relu(ATT2 @ A1 + att2_b); logit = dot(att3_w, A2_row)
    float pA = 0.f, pB = 0.f;
    #pragma unroll
    for (int m = 0; m < 4; ++m){
      const f32x4 bi = bl[4*16 + 4*m];
      f32x4 aA = bi, aB = bi;
      #pragma unroll
      for (int s = 0; s < 2; ++s){
        Frag w; w.u4 = wl[(56 + m*2 + s) * 64];
        aA = __builtin_amdgcn_mfma_f32_16x16x32_bf16(w.b, b4A[s].b, aA, 0, 0, 0);
        aB = __builtin_amdgcn_mfma_f32_16x16x32_bf16(w.b, b4B[s].b, aB, 0, 0, 0);
      }
      aA = relu4(aA); aB = relu4(aB);
      const f32x4 a3m = bl[5*16 + 4*m];
      #pragma unroll
      for (int j = 0; j < 4; ++j){
        pA = fmaf(a3m[j], aA[j], pA);
        pB = fmaf(a3m[j], aB[j], pB);
      }
    }
    pA += __shfl_xor(pA, 16); pA += __shfl_xor(pA, 32);
    pB += __shfl_xor(pB, 16); pB += __shfl_xor(pB, 32);

    // max-free online softmax (logits O(1e-2); guard at 60); es-reduce deferred
    const float eA = vA ? __expf(fminf(pA, 60.f)) : 0.f;
    const float eB = vB ? __expf(fminf(pB, 60.f)) : 0.f;
    swl += eA + eB;
    #pragma unroll
    for (int m = 0; m < 4; ++m)
      #pragma unroll
      for (int j = 0; j < 4; ++j)
        accw[m][j] = fmaf(eA, OGA[m][j], fmaf(eB, OGB[m][j], accw[m][j]));
  }

  // finale: reduce over the 16 row-lanes (accw and swl), scale, store
  #pragma unroll
  for (int o = 1; o < 16; o <<= 1){
    #pragma unroll
    for (int m = 0; m < 4; ++m)
      #pragma unroll
      for (int j = 0; j < 4; ++j)
        accw[m][j] += __shfl_xor(accw[m][j], o);
    swl += __shfl_xor(swl, o);
  }
  if (r16 == 0){
    const float inv = 1.f / swl;
    #pragma unroll
    for (int m = 0; m < 4; ++m){
      f32x4 v = accw[m];
      #pragma unroll
      for (int j = 0; j < 4; ++j) v[j] *= inv;
      *(f32x4*)(out + (size_t)n * 64 + 16*m + 4*g) = v;
    }
  }
}

extern "C" void kernel_launch(void* const* d_in, const int* in_sizes, int n_in,
                              void* d_out, int out_size, void* d_ws, size_t ws_size,
                              hipStream_t stream){
  const int*   nodes = (const int*)  d_in[0];
  const int*   huv   = (const int*)  d_in[1];
  const int*   hr    = (const int*)  d_in[2];
  const float* u2e   = (const float*)d_in[3];
  const float* v2e   = (const float*)d_in[4];
  const float* r2e   = (const float*)d_in[5];
  const float* w1    = (const float*)d_in[6];
  const float* b1    = (const float*)d_in[7];
  const float* w2    = (const float*)d_in[8];
  const float* b2    = (const float*)d_in[9];
  const float* muw   = (const float*)d_in[10];
  const float* mub   = (const float*)d_in[11];
  const float* a1w   = (const float*)d_in[12];
  const float* a1b   = (const float*)d_in[13];
  const float* a2w   = (const float*)d_in[14];
  const float* a2b   = (const float*)d_in[15];
  const float* a3w   = (const float*)d_in[16];
  // d_in[17] = att3_b: constant logit offset -> cancels in softmax.

  const int N = in_sizes[0];            // 2048
  uint4* ws = (uint4*)d_ws;             // 74 KiB: frag table + r2e frags

  hipLaunchKernelGGL(prep_weights, dim3(74), dim3(64), 0, stream,
                     w1, w2, muw, a1w, a2w, r2e, ws);
  hipLaunchKernelGGL(uv_agg_main, dim3(N / 4), dim3(256), 0, stream,
                     nodes, huv, hr, u2e, v2e,
                     b1, b2, mub, a1b, a2b, a3w,
                     (const uint4*)ws, (float*)d_out);
}

// Round 10
// 102.694 us; speedup vs baseline: 1.4233x; 1.4233x over previous
//
#include <hip/hip_runtime.h>
#include <hip/hip_bf16.h>

typedef float f32x4 __attribute__((ext_vector_type(4)));
typedef __bf16 bf16x8 __attribute__((ext_vector_type(8)));

union Frag { unsigned short h[8]; unsigned int u[4]; uint4 u4; bf16x8 b; };

__device__ __forceinline__ unsigned short f2bs(float f){
  __hip_bfloat16 v = __float2bfloat16(f);
  return __builtin_bit_cast(unsigned short, v);
}
// 1-instruction bf16 pair pack (RNE)
__device__ __forceinline__ unsigned int pk2(float a, float b){
  unsigned int r;
  asm("v_cvt_pk_bf16_f32 %0, %1, %2" : "=v"(r) : "v"(a), "v"(b));
  return r;
}
__device__ __forceinline__ Frag packF(f32x4 a, f32x4 b){
  Frag f;
  f.u[0] = pk2(a[0], a[1]); f.u[1] = pk2(a[2], a[3]);
  f.u[2] = pk2(b[0], b[1]); f.u[3] = pk2(b[2], b[3]);
  return f;
}
__device__ __forceinline__ f32x4 relu4(f32x4 v){
  f32x4 r;
  #pragma unroll
  for (int j = 0; j < 4; ++j) r[j] = fmaxf(v[j], 0.f);
  return r;
}
__device__ __forceinline__ float sigmoid_fast(float x){
  return __builtin_amdgcn_rcpf(1.f + __expf(-x));
}

// ---------------------------------------------------------------------------
// Prep: weight matrices -> MFMA A-frag order bf16 (ws[0..4095] uint4), plus
// r2e's 5 rows pre-packed as B-frag pairs (ws[4096..4735]).
// A-frag element (h,j): W[16*m + (lane&15)][32*s + 16*h + 4*(lane>>4) + j]
// ---------------------------------------------------------------------------
__global__ void prep_weights(const float* __restrict__ w1, const float* __restrict__ w2,
                             const float* __restrict__ mu, const float* __restrict__ a1,
                             const float* __restrict__ a2, const float* __restrict__ r2e,
                             uint4* __restrict__ ws){
  const int f = blockIdx.x;
  const int l = threadIdx.x;
  Frag fr;
  if (f < 64){
    const float* W; int m, s, K;
    if (f < 16)      { W = w1; m = f >> 2;        s = f & 3;        K = 128; }
    else if (f < 24) { W = w2; m = (f - 16) >> 1; s = (f - 16) & 1; K = 64;  }
    else if (f < 40) { W = mu; m = (f - 24) >> 2; s = (f - 24) & 3; K = 128; }
    else if (f < 56) { W = a1; m = (f - 40) >> 2; s = (f - 40) & 3; K = 128; }
    else             { W = a2; m = (f - 56) >> 1; s = (f - 56) & 1; K = 64;  }
    const int row = 16 * m + (l & 15);
    const int k0  = 32 * s + 4 * (l >> 4);
    #pragma unroll
    for (int h = 0; h < 2; ++h)
      #pragma unroll
      for (int j = 0; j < 4; ++j)
        fr.h[4*h + j] = f2bs(W[row * K + k0 + 16*h + j]);
    ws[f * 64 + l] = fr.u4;
  } else {
    const int f2 = f - 64;            // 0..9
    const int R = f2 >> 1, sp = f2 & 1;
    const int g = (l >> 4) & 3;
    #pragma unroll
    for (int h = 0; h < 2; ++h)
      #pragma unroll
      for (int j = 0; j < 4; ++j)
        fr.h[4*h + j] = f2bs(r2e[R * 64 + sp * 32 + 16*h + 4*g + j]);
    ws[4096 + f2 * 64 + l] = fr.u4;
  }
}

// ---------------------------------------------------------------------------
// Main: grid 512 x 256thr, wave w owns node n = b*4+w, dual-chunk pipeline
// (round-6 structure, LDS weight table restored: round 9 proved L2 weights
// are 3x WORSE in this structure - latency exposed on the MFMA chain).
// Round-10 delta: SOFTWARE-PIPELINED WEIGHT READS. Stage s+1's weight frags
// are ds_read into a register ping-pong (wS1/wS2, 16 frags each) while stage
// s's MFMAs execute, taking the ~120cy LDS latency off the dependent chain.
// Buffer roles alternate per iteration -> 2-iteration-unrolled loop (3 trips,
// not unrolled further) + tail; all frag indexing compile-time static.
// OG is kept only as packed bf16 (bg frags); the weighted accumulation
// unpacks from bg (saves 32 live f32 regs; adds ~2e-4 error, budget 2.37e-3).
// NOTE: no min-waves launch_bounds arg (round 3: forced cap => ~1GB spill).
// LDS (77312 B): [0,65536) uint4 wlds[4096]; [65536,67072) float bias[384];
//                [67072,77312) uint4 rlds[640]
// ---------------------------------------------------------------------------
__global__ __launch_bounds__(256)
void uv_agg_main(const int* __restrict__ nodes, const int* __restrict__ huv,
                 const int* __restrict__ hr, const float* __restrict__ u2e,
                 const float* __restrict__ v2e,
                 const float* __restrict__ b1g, const float* __restrict__ b2g,
                 const float* __restrict__ bmg, const float* __restrict__ ba1g,
                 const float* __restrict__ ba2g, const float* __restrict__ a3g,
                 const uint4* __restrict__ wsfrag, float* __restrict__ out){
  extern __shared__ unsigned char smem[];
  uint4* wlds = (uint4*)smem;
  float* bias = (float*)(smem + 65536);
  uint4* rlds = (uint4*)(smem + 67072);

  const int tid  = threadIdx.x;
  const int lane = tid & 63;
  const int wave = tid >> 6;
  const int g    = lane >> 4;
  const int r16  = lane & 15;
  const int n    = blockIdx.x * 4 + wave;

  // stage weight frag table + r2e frags + biases into LDS
  #pragma unroll 4
  for (int i = tid; i < 4096; i += 256) wlds[i] = wsfrag[i];
  for (int i = tid; i < 640; i += 256)  rlds[i] = wsfrag[4096 + i];
  if (tid < 384){
    const int w = tid >> 6, d = tid & 63;
    const float* src = (w==0)?b1g:(w==1)?b2g:(w==2)?bmg:(w==3)?ba1g:(w==4)?ba2g:a3g;
    bias[tid] = src[d];
  }
  __syncthreads();

  const uint4* wl = wlds + lane;
  const f32x4* bl = (const f32x4*)bias + g;
  const unsigned char* rbase = (const unsigned char*)rlds + lane * 16;
  const int* hu  = huv + n * 200;
  const int* hrw = hr  + n * 200;

  // per-node q = v2e[nodes[n]]
  const int item = nodes[n];
  f32x4 qv[4];
  #pragma unroll
  for (int m = 0; m < 4; ++m)
    qv[m] = *(const f32x4*)(v2e + (size_t)item * 64 + 16*m + 4*g);
  Frag qf[2];
  qf[0] = packF(qv[0], qv[1]); qf[1] = packF(qv[2], qv[3]);

  float swl = 0.f;                 // per-lane exp-sum (reduced in finale)
  f32x4 accw[4];
  #pragma unroll
  for (int m = 0; m < 4; ++m) accw[m] = (f32x4)(0.f);

  // initial gather: tiles 0 and 1
  int irA, irB;
  f32x4 urA[4], urB[4];
  {
    const int iuA = hu[r16];      irA = hrw[r16];
    const int iuB = hu[16 + r16]; irB = hrw[16 + r16];
    const f32x4* ua = (const f32x4*)(u2e + (size_t)iuA * 64);
    const f32x4* ub = (const f32x4*)(u2e + (size_t)iuB * 64);
    #pragma unroll
    for (int s = 0; s < 4; ++s){ urA[s] = ua[4*s + g]; urB[s] = ub[4*s + g]; }
  }

  // weight register ping-pong; preload S1 into wS1
  Frag wS1[16], wS2[16];
  #pragma unroll
  for (int i = 0; i < 16; ++i) wS1[i].u4 = wl[i * 64];

  auto body = [&](Frag (&wC)[16], Frag (&wN)[16], int it, bool hasNext){
    Frag b0A[2], b0B[2];
    b0A[0] = packF(urA[0], urA[1]); b0A[1] = packF(urA[2], urA[3]);
    b0B[0] = packF(urB[0], urB[1]); b0B[1] = packF(urB[2], urB[3]);
    const int ircA = irA, ircB = irB;
    const bool vA = (32*it + r16) < 200;
    const bool vB = (32*it + 16 + r16) < 200;

    // gather prefetch for next iteration (independent of this chain)
    if (hasNext){
      const int base = 32*it + 32;
      const int kA = min(base + r16, 199);
      const int kB = min(base + 16 + r16, 199);
      const int iuA = hu[kA]; irA = hrw[kA];
      const int iuB = hu[kB]; irB = hrw[kB];
      const f32x4* ua = (const f32x4*)(u2e + (size_t)iuA * 64);
      const f32x4* ub = (const f32x4*)(u2e + (size_t)iuB * 64);
      #pragma unroll
      for (int s = 0; s < 4; ++s){ urA[s] = ua[4*s + g]; urB[s] = ub[4*s + g]; }
    }

    // issue S2 weight loads (wN[0:8]) ahead of S1 compute
    #pragma unroll
    for (int i = 0; i < 8; ++i) wN[i].u4 = wl[(16 + i) * 64];

    // S1: X = relu(W1 @ concat(e_uv, e_r) + b1)
    f32x4 XA[4], XB[4];
    #pragma unroll
    for (int m = 0; m < 4; ++m){
      const f32x4 bi = bl[0*16 + 4*m];
      f32x4 aA = bi, aB = bi;
      #pragma unroll
      for (int s = 0; s < 4; ++s){
        Frag eA, eB;
        if (s < 2){ eA = b0A[s]; eB = b0B[s]; }
        else {
          eA.u4 = *(const uint4*)(rbase + (size_t)(ircA*2 + (s-2)) * 1024);
          eB.u4 = *(const uint4*)(rbase + (size_t)(ircB*2 + (s-2)) * 1024);
        }
        aA = __builtin_amdgcn_mfma_f32_16x16x32_bf16(wC[m*4 + s].b, eA.b, aA, 0, 0, 0);
        aB = __builtin_amdgcn_mfma_f32_16x16x32_bf16(wC[m*4 + s].b, eB.b, aB, 0, 0, 0);
      }
      XA[m] = relu4(aA); XB[m] = relu4(aB);
    }
    Frag bxA[2], bxB[2];
    bxA[0] = packF(XA[0], XA[1]); bxA[1] = packF(XA[2], XA[3]);
    bxB[0] = packF(XB[0], XB[1]); bxB[1] = packF(XB[2], XB[3]);

    // issue S3 weight loads (wC, free after S1)
    #pragma unroll
    for (int i = 0; i < 16; ++i) wC[i].u4 = wl[(24 + i) * 64];

    // S2: O = relu(W2 @ X + b2)   [weights wN[0:8]]
    f32x4 OA[4], OB[4];
    #pragma unroll
    for (int m = 0; m < 4; ++m){
      const f32x4 bi = bl[1*16 + 4*m];
      f32x4 aA = bi, aB = bi;
      #pragma unroll
      for (int s = 0; s < 2; ++s){
        aA = __builtin_amdgcn_mfma_f32_16x16x32_bf16(wN[m*2 + s].b, bxA[s].b, aA, 0, 0, 0);
        aB = __builtin_amdgcn_mfma_f32_16x16x32_bf16(wN[m*2 + s].b, bxB[s].b, aB, 0, 0, 0);
      }
      OA[m] = relu4(aA); OB[m] = relu4(aB);
    }
    Frag boA[2], boB[2];
    boA[0] = packF(OA[0], OA[1]); boA[1] = packF(OA[2], OA[3]);
    boB[0] = packF(OB[0], OB[1]); boB[1] = packF(OB[2], OB[3]);

    // issue S4 weight loads (wN, free after S2)
    #pragma unroll
    for (int i = 0; i < 16; ++i) wN[i].u4 = wl[(40 + i) * 64];

    // S3: gate = sigmoid(MU @ concat(O,q) + mu_b); OG = q + gate*(O-q)
    // OG kept only as packed bf16 (bg)  [weights wC]
    Frag bgA[2], bgB[2];
    #pragma unroll
    for (int m = 0; m < 4; ++m){
      const f32x4 bi = bl[2*16 + 4*m];
      f32x4 aA = bi, aB = bi;
      #pragma unroll
      for (int s = 0; s < 4; ++s){
        const bf16x8 eA = (s < 2) ? boA[s].b : qf[s-2].b;
        const bf16x8 eB = (s < 2) ? boB[s].b : qf[s-2].b;
        aA = __builtin_amdgcn_mfma_f32_16x16x32_bf16(wC[m*4 + s].b, eA, aA, 0, 0, 0);
        aB = __builtin_amdgcn_mfma_f32_16x16x32_bf16(wC[m*4 + s].b, eB, aB, 0, 0, 0);
      }
      f32x4 ogA, ogB;
      #pragma unroll
      for (int j = 0; j < 4; ++j){
        const float gA = sigmoid_fast(aA[j]);
        const float gB = sigmoid_fast(aB[j]);
        ogA[j] = fmaf(gA, OA[m][j] - qv[m][j], qv[m][j]);
        ogB[j] = fmaf(gB, OB[m][j] - qv[m][j], qv[m][j]);
      }
      bgA[m >> 1].u[(m & 1)*2 + 0] = pk2(ogA[0], ogA[1]);
      bgA[m >> 1].u[(m & 1)*2 + 1] = pk2(ogA[2], ogA[3]);
      bgB[m >> 1].u[(m & 1)*2 + 0] = pk2(ogB[0], ogB[1]);
      bgB[m >> 1].u[(m & 1)*2 + 1] = pk2(ogB[2], ogB[3]);
    }

    // issue S5 weight loads (wC[0:8], free after S3)
    #pragma unroll
    for (int i = 0; i < 8; ++i) wC[i].u4 = wl[(56 + i) * 64];

    // S4: A1 = relu(ATT1 @ concat(OG,q) + att1_b)   [weights wN]
    f32x4 A1A[4], A1B[4];
    #pragma unroll
    for (int m = 0; m < 4; ++m){
      const f32x4 bi = bl[3*16 + 4*m];
      f32x4 aA = bi, aB = bi;
      #pragma unroll
      for (int s = 0; s < 4; ++s){
        const bf16x8 eA = (s < 2) ? bgA[s].b : qf[s-2].b;
        const bf16x8 eB = (s < 2) ? bgB[s].b : qf[s-2].b;
        aA = __builtin_amdgcn_mfma_f32_16x16x32_bf16(wN[m*4 + s].b, eA, aA, 0, 0, 0);
        aB = __builtin_amdgcn_mfma_f32_16x16x32_bf16(wN[m*4 + s].b, eB, aB, 0, 0, 0);
      }
      A1A[m] = relu4(aA); A1B[m] = relu4(aB);
    }
    Frag b4A[2], b4B[2];
    b4A[0] = packF(A1A[0], A1A[1]); b4A[1] = packF(A1A[2], A1A[3]);
    b4B[0] = packF(A1B[0], A1B[1]); b4B[1] = packF(A1B[2], A1B[3]);

    // issue next-iteration S1 loads (wN, free after S4) under S5+softmax
    if (hasNext){
      #pragma unroll
      for (int i = 0; i < 16; ++i) wN[i].u4 = wl[i * 64];
    }

    // S5: A2 = relu(ATT2 @ A1 + att2_b); logit = dot(att3_w, A2_row)
    float pA = 0.f, pB = 0.f;
    #pragma unroll
    for (int m = 0; m < 4; ++m){
      const f32x4 bi = bl[4*16 + 4*m];
      f32x4 aA = bi, aB = bi;
      #pragma unroll
      for (int s = 0; s < 2; ++s){
        aA = __builtin_amdgcn_mfma_f32_16x16x32_bf16(wC[m*2 + s].b, b4A[s].b, aA, 0, 0, 0);
        aB = __builtin_amdgcn_mfma_f32_16x16x32_bf16(wC[m*2 + s].b, b4B[s].b, aB, 0, 0, 0);
      }
      aA = relu4(aA); aB = relu4(aB);
      const f32x4 a3m = bl[5*16 + 4*m];
      #pragma unroll
      for (int j = 0; j < 4; ++j){
        pA = fmaf(a3m[j], aA[j], pA);
        pB = fmaf(a3m[j], aB[j], pB);
      }
    }
    pA += __shfl_xor(pA, 16); pA += __shfl_xor(pA, 32);
    pB += __shfl_xor(pB, 16); pB += __shfl_xor(pB, 32);

    // max-free online softmax (logits O(1e-2); guard at 60); es deferred
    const float eA = vA ? __expf(fminf(pA, 60.f)) : 0.f;
    const float eB = vB ? __expf(fminf(pB, 60.f)) : 0.f;
    swl += eA + eB;
    // accumulate OG from packed bf16 (bg)
    #pragma unroll
    for (int m = 0; m < 4; ++m)
      #pragma unroll
      for (int j = 0; j < 4; ++j){
        const unsigned int ba = bgA[m >> 1].u[(m & 1)*2 + (j >> 1)];
        const unsigned int bb = bgB[m >> 1].u[(m & 1)*2 + (j >> 1)];
        const float oA = __builtin_bit_cast(float, (j & 1) ? (ba & 0xffff0000u) : (ba << 16));
        const float oB = __builtin_bit_cast(float, (j & 1) ? (bb & 0xffff0000u) : (bb << 16));
        accw[m][j] = fmaf(eA, oA, fmaf(eB, oB, accw[m][j]));
      }
  };

  // 7 iterations: 3 unrolled pairs (roles alternate) + tail
  #pragma unroll 1
  for (int p = 0; p < 3; ++p){
    body(wS1, wS2, 2*p,     true);
    body(wS2, wS1, 2*p + 1, true);
  }
  body(wS1, wS2, 6, false);

  // finale: reduce over the 16 row-lanes (accw and swl), scale, store
  #pragma unroll
  for (int o = 1; o < 16; o <<= 1){
    #pragma unroll
    for (int m = 0; m < 4; ++m)
      #pragma unroll
      for (int j = 0; j < 4; ++j)
        accw[m][j] += __shfl_xor(accw[m][j], o);
    swl += __shfl_xor(swl, o);
  }
  if (r16 == 0){
    const float inv = 1.f / swl;
    #pragma unroll
    for (int m = 0; m < 4; ++m){
      f32x4 v = accw[m];
      #pragma unroll
      for (int j = 0; j < 4; ++j) v[j] *= inv;
      *(f32x4*)(out + (size_t)n * 64 + 16*m + 4*g) = v;
    }
  }
}

extern "C" void kernel_launch(void* const* d_in, const int* in_sizes, int n_in,
                              void* d_out, int out_size, void* d_ws, size_t ws_size,
                              hipStream_t stream){
  const int*   nodes = (const int*)  d_in[0];
  const int*   huv   = (const int*)  d_in[1];
  const int*   hr    = (const int*)  d_in[2];
  const float* u2e   = (const float*)d_in[3];
  const float* v2e   = (const float*)d_in[4];
  const float* r2e   = (const float*)d_in[5];
  const float* w1    = (const float*)d_in[6];
  const float* b1    = (const float*)d_in[7];
  const float* w2    = (const float*)d_in[8];
  const float* b2    = (const float*)d_in[9];
  const float* muw   = (const float*)d_in[10];
  const float* mub   = (const float*)d_in[11];
  const float* a1w   = (const float*)d_in[12];
  const float* a1b   = (const float*)d_in[13];
  const float* a2w   = (const float*)d_in[14];
  const float* a2b   = (const float*)d_in[15];
  const float* a3w   = (const float*)d_in[16];
  // d_in[17] = att3_b: constant logit offset -> cancels in softmax.

  const int N = in_sizes[0];            // 2048
  uint4* ws = (uint4*)d_ws;             // 74 KiB: frag table + r2e frags

  hipLaunchKernelGGL(prep_weights, dim3(74), dim3(64), 0, stream,
                     w1, w2, muw, a1w, a2w, r2e, ws);
  hipLaunchKernelGGL(uv_agg_main, dim3(N / 4), dim3(256), 77312, stream,
                     nodes, huv, hr, u2e, v2e,
                     b1, b2, mub, a1b, a2b, a3w,
                     (const uint4*)ws, (float*)d_out);
}

// Round 11
// 79.751 us; speedup vs baseline: 1.8327x; 1.2877x over previous
//
#include <hip/hip_runtime.h>
#include <hip/hip_bf16.h>

typedef float f32x4 __attribute__((ext_vector_type(4)));
typedef __bf16 bf16x8 __attribute__((ext_vector_type(8)));

union Frag { unsigned short h[8]; unsigned int u[4]; uint4 u4; bf16x8 b; };

__device__ __forceinline__ unsigned short f2bs(float f){
  __hip_bfloat16 v = __float2bfloat16(f);
  return __builtin_bit_cast(unsigned short, v);
}
// 1-instruction bf16 pair pack (RNE)
__device__ __forceinline__ unsigned int pk2(float a, float b){
  unsigned int r;
  asm("v_cvt_pk_bf16_f32 %0, %1, %2" : "=v"(r) : "v"(a), "v"(b));
  return r;
}
__device__ __forceinline__ Frag packF(f32x4 a, f32x4 b){
  Frag f;
  f.u[0] = pk2(a[0], a[1]); f.u[1] = pk2(a[2], a[3]);
  f.u[2] = pk2(b[0], b[1]); f.u[3] = pk2(b[2], b[3]);
  return f;
}
__device__ __forceinline__ f32x4 relu4(f32x4 v){
  f32x4 r;
  #pragma unroll
  for (int j = 0; j < 4; ++j) r[j] = fmaxf(v[j], 0.f);
  return r;
}
__device__ __forceinline__ float sigmoid_fast(float x){
  return __builtin_amdgcn_rcpf(1.f + __expf(-x));
}

// ---------------------------------------------------------------------------
// Prep: weight matrices -> MFMA A-frag order bf16 (ws[0..4095] uint4), plus
// r2e's 5 rows pre-packed as B-frag pairs (ws[4096..4735]).
// A-frag element (h,j): W[16*m + (lane&15)][32*s + 16*h + 4*(lane>>4) + j]
// ---------------------------------------------------------------------------
__global__ void prep_weights(const float* __restrict__ w1, const float* __restrict__ w2,
                             const float* __restrict__ mu, const float* __restrict__ a1,
                             const float* __restrict__ a2, const float* __restrict__ r2e,
                             uint4* __restrict__ ws){
  const int f = blockIdx.x;
  const int l = threadIdx.x;
  Frag fr;
  if (f < 64){
    const float* W; int m, s, K;
    if (f < 16)      { W = w1; m = f >> 2;        s = f & 3;        K = 128; }
    else if (f < 24) { W = w2; m = (f - 16) >> 1; s = (f - 16) & 1; K = 64;  }
    else if (f < 40) { W = mu; m = (f - 24) >> 2; s = (f - 24) & 3; K = 128; }
    else if (f < 56) { W = a1; m = (f - 40) >> 2; s = (f - 40) & 3; K = 128; }
    else             { W = a2; m = (f - 56) >> 1; s = (f - 56) & 1; K = 64;  }
    const int row = 16 * m + (l & 15);
    const int k0  = 32 * s + 4 * (l >> 4);
    #pragma unroll
    for (int h = 0; h < 2; ++h)
      #pragma unroll
      for (int j = 0; j < 4; ++j)
        fr.h[4*h + j] = f2bs(W[row * K + k0 + 16*h + j]);
    ws[f * 64 + l] = fr.u4;
  } else {
    const int f2 = f - 64;            // 0..9
    const int R = f2 >> 1, sp = f2 & 1;
    const int g = (l >> 4) & 3;
    #pragma unroll
    for (int h = 0; h < 2; ++h)
      #pragma unroll
      for (int j = 0; j < 4; ++j)
        fr.h[4*h + j] = f2bs(r2e[R * 64 + sp * 32 + 16*h + 4*g + j]);
    ws[4096 + f2 * 64 + l] = fr.u4;
  }
}

// ---------------------------------------------------------------------------
// TRI-CHUNK body: NC tiles (16 rows each) flow through the 5-stage chain as
// independent interleaved MFMA/VALU streams; each LDS weight read serves all
// NC chunks. NN tiles are gather-prefetched (packed to bf16 immediately) for
// the next iteration. All chunk loops fully unrolled -> static indexing.
// Register budget lesson (r10): weight frags in regs (128) blew the 256
// unified budget -> 117MB spill. Tri-chunk costs ~+50 regs; fits.
// ---------------------------------------------------------------------------
template<int NC, int NN>
__device__ __forceinline__ void body(
    int tb, int tnb,
    const uint4* wl, const f32x4* bl, const unsigned char* rbase,
    const int* hu, const int* hrw, const float* u2e,
    int r16, int g,
    const Frag (&qf)[2], const f32x4 (&qv)[4],
    Frag (&nb0)[3][2], int (&ir)[3],
    f32x4 (&accw)[4], float& swl)
{
  Frag b0[3][2]; int irc[3]; bool v[3];
  #pragma unroll
  for (int c = 0; c < NC; ++c){
    b0[c][0] = nb0[c][0]; b0[c][1] = nb0[c][1];
    irc[c] = ir[c];
    v[c] = (16*(tb + c) + r16) < 200;
  }
  // gather-prefetch next NN tiles (independent of this iteration's chains)
  #pragma unroll
  for (int c = 0; c < NN; ++c){
    const int k = min(16*(tnb + c) + r16, 199);
    const int iu = hu[k]; ir[c] = hrw[k];
    const f32x4* ua = (const f32x4*)(u2e + (size_t)iu * 64);
    nb0[c][0] = packF(ua[g], ua[4+g]);
    nb0[c][1] = packF(ua[8+g], ua[12+g]);
  }

  // S1: X = relu(W1 @ concat(e_uv, e_r) + b1)
  f32x4 X[3][4];
  #pragma unroll
  for (int m = 0; m < 4; ++m){
    const f32x4 bi = bl[0*16 + 4*m];
    f32x4 a[3];
    #pragma unroll
    for (int c = 0; c < NC; ++c) a[c] = bi;
    #pragma unroll
    for (int s = 0; s < 4; ++s){
      Frag w; w.u4 = wl[(m*4 + s) * 64];
      #pragma unroll
      for (int c = 0; c < NC; ++c){
        Frag e;
        if (s < 2) e = b0[c][s];
        else e.u4 = *(const uint4*)(rbase + (size_t)(irc[c]*2 + (s-2)) * 1024);
        a[c] = __builtin_amdgcn_mfma_f32_16x16x32_bf16(w.b, e.b, a[c], 0, 0, 0);
      }
    }
    #pragma unroll
    for (int c = 0; c < NC; ++c) X[c][m] = relu4(a[c]);
  }
  Frag bx[3][2];
  #pragma unroll
  for (int c = 0; c < NC; ++c){
    bx[c][0] = packF(X[c][0], X[c][1]);
    bx[c][1] = packF(X[c][2], X[c][3]);
  }

  // S2: O = relu(W2 @ X + b2)
  f32x4 O[3][4];
  #pragma unroll
  for (int m = 0; m < 4; ++m){
    const f32x4 bi = bl[1*16 + 4*m];
    f32x4 a[3];
    #pragma unroll
    for (int c = 0; c < NC; ++c) a[c] = bi;
    #pragma unroll
    for (int s = 0; s < 2; ++s){
      Frag w; w.u4 = wl[(16 + m*2 + s) * 64];
      #pragma unroll
      for (int c = 0; c < NC; ++c)
        a[c] = __builtin_amdgcn_mfma_f32_16x16x32_bf16(w.b, bx[c][s].b, a[c], 0, 0, 0);
    }
    #pragma unroll
    for (int c = 0; c < NC; ++c) O[c][m] = relu4(a[c]);
  }
  Frag bo[3][2];
  #pragma unroll
  for (int c = 0; c < NC; ++c){
    bo[c][0] = packF(O[c][0], O[c][1]);
    bo[c][1] = packF(O[c][2], O[c][3]);
  }

  // S3: gate = sigmoid(MU @ concat(O,q) + mu_b); OG = q + gate*(O-q)
  // OG kept only as packed bf16 (r10-verified numerics)
  Frag bg[3][2];
  #pragma unroll
  for (int m = 0; m < 4; ++m){
    const f32x4 bi = bl[2*16 + 4*m];
    f32x4 a[3];
    #pragma unroll
    for (int c = 0; c < NC; ++c) a[c] = bi;
    #pragma unroll
    for (int s = 0; s < 4; ++s){
      Frag w; w.u4 = wl[(24 + m*4 + s) * 64];
      #pragma unroll
      for (int c = 0; c < NC; ++c){
        const bf16x8 e = (s < 2) ? bo[c][s].b : qf[s-2].b;
        a[c] = __builtin_amdgcn_mfma_f32_16x16x32_bf16(w.b, e, a[c], 0, 0, 0);
      }
    }
    #pragma unroll
    for (int c = 0; c < NC; ++c){
      f32x4 og;
      #pragma unroll
      for (int j = 0; j < 4; ++j){
        const float gg = sigmoid_fast(a[c][j]);
        og[j] = fmaf(gg, O[c][m][j] - qv[m][j], qv[m][j]);
      }
      bg[c][m >> 1].u[(m & 1)*2 + 0] = pk2(og[0], og[1]);
      bg[c][m >> 1].u[(m & 1)*2 + 1] = pk2(og[2], og[3]);
    }
  }

  // S4: A1 = relu(ATT1 @ concat(OG,q) + att1_b)
  f32x4 A1[3][4];
  #pragma unroll
  for (int m = 0; m < 4; ++m){
    const f32x4 bi = bl[3*16 + 4*m];
    f32x4 a[3];
    #pragma unroll
    for (int c = 0; c < NC; ++c) a[c] = bi;
    #pragma unroll
    for (int s = 0; s < 4; ++s){
      Frag w; w.u4 = wl[(40 + m*4 + s) * 64];
      #pragma unroll
      for (int c = 0; c < NC; ++c){
        const bf16x8 e = (s < 2) ? bg[c][s].b : qf[s-2].b;
        a[c] = __builtin_amdgcn_mfma_f32_16x16x32_bf16(w.b, e, a[c], 0, 0, 0);
      }
    }
    #pragma unroll
    for (int c = 0; c < NC; ++c) A1[c][m] = relu4(a[c]);
  }
  Frag b4[3][2];
  #pragma unroll
  for (int c = 0; c < NC; ++c){
    b4[c][0] = packF(A1[c][0], A1[c][1]);
    b4[c][1] = packF(A1[c][2], A1[c][3]);
  }

  // S5: A2 = relu(ATT2 @ A1 + att2_b); logit = dot(att3_w, A2_row)
  float p[3] = {0.f, 0.f, 0.f};
  #pragma unroll
  for (int m = 0; m < 4; ++m){
    const f32x4 bi = bl[4*16 + 4*m];
    f32x4 a[3];
    #pragma unroll
    for (int c = 0; c < NC; ++c) a[c] = bi;
    #pragma unroll
    for (int s = 0; s < 2; ++s){
      Frag w; w.u4 = wl[(56 + m*2 + s) * 64];
      #pragma unroll
      for (int c = 0; c < NC; ++c)
        a[c] = __builtin_amdgcn_mfma_f32_16x16x32_bf16(w.b, b4[c][s].b, a[c], 0, 0, 0);
    }
    const f32x4 a3m = bl[5*16 + 4*m];
    #pragma unroll
    for (int c = 0; c < NC; ++c){
      const f32x4 r = relu4(a[c]);
      #pragma unroll
      for (int j = 0; j < 4; ++j) p[c] = fmaf(a3m[j], r[j], p[c]);
    }
  }
  float e[3];
  #pragma unroll
  for (int c = 0; c < NC; ++c){
    p[c] += __shfl_xor(p[c], 16);
    p[c] += __shfl_xor(p[c], 32);
    // max-free online softmax (logits O(1e-2); guard 60); es-reduce deferred
    e[c] = v[c] ? __expf(fminf(p[c], 60.f)) : 0.f;
    swl += e[c];
  }
  // accumulate OG from packed bf16
  #pragma unroll
  for (int m = 0; m < 4; ++m)
    #pragma unroll
    for (int j = 0; j < 4; ++j){
      float acc = accw[m][j];
      #pragma unroll
      for (int c = 0; c < NC; ++c){
        const unsigned int bb = bg[c][m >> 1].u[(m & 1)*2 + (j >> 1)];
        const float o = __builtin_bit_cast(float, (j & 1) ? (bb & 0xffff0000u) : (bb << 16));
        acc = fmaf(e[c], o, acc);
      }
      accw[m][j] = acc;
    }
}

// ---------------------------------------------------------------------------
// Main: grid 512 x 256thr, wave w owns node n = b*4+w end-to-end. Tri-chunk:
// 4 iterations of 3 tiles (0..11) + single-chunk tail (tile 12). Weight table
// in LDS (r9: L2 weights 3x worse), per-lane deferred es-sum (r9-verified),
// packed-OG (r10-verified). NOTE: no min-waves launch_bounds (r3: cap=spill).
// LDS (77312 B): [0,65536) uint4 wlds[4096]; [65536,67072) float bias[384];
//                [67072,77312) uint4 rlds[640]
// ---------------------------------------------------------------------------
__global__ __launch_bounds__(256)
void uv_agg_main(const int* __restrict__ nodes, const int* __restrict__ huv,
                 const int* __restrict__ hr, const float* __restrict__ u2e,
                 const float* __restrict__ v2e,
                 const float* __restrict__ b1g, const float* __restrict__ b2g,
                 const float* __restrict__ bmg, const float* __restrict__ ba1g,
                 const float* __restrict__ ba2g, const float* __restrict__ a3g,
                 const uint4* __restrict__ wsfrag, float* __restrict__ out){
  extern __shared__ unsigned char smem[];
  uint4* wlds = (uint4*)smem;
  float* bias = (float*)(smem + 65536);
  uint4* rlds = (uint4*)(smem + 67072);

  const int tid  = threadIdx.x;
  const int lane = tid & 63;
  const int wave = tid >> 6;
  const int g    = lane >> 4;
  const int r16  = lane & 15;
  const int n    = blockIdx.x * 4 + wave;

  // stage weight frag table + r2e frags + biases into LDS
  #pragma unroll 4
  for (int i = tid; i < 4096; i += 256) wlds[i] = wsfrag[i];
  for (int i = tid; i < 640; i += 256)  rlds[i] = wsfrag[4096 + i];
  if (tid < 384){
    const int w = tid >> 6, d = tid & 63;
    const float* src = (w==0)?b1g:(w==1)?b2g:(w==2)?bmg:(w==3)?ba1g:(w==4)?ba2g:a3g;
    bias[tid] = src[d];
  }
  __syncthreads();

  const uint4* wl = wlds + lane;
  const f32x4* bl = (const f32x4*)bias + g;
  const unsigned char* rbase = (const unsigned char*)rlds + lane * 16;
  const int* hu  = huv + n * 200;
  const int* hrw = hr  + n * 200;

  // per-node q = v2e[nodes[n]]
  const int item = nodes[n];
  f32x4 qv[4];
  #pragma unroll
  for (int m = 0; m < 4; ++m)
    qv[m] = *(const f32x4*)(v2e + (size_t)item * 64 + 16*m + 4*g);
  Frag qf[2];
  qf[0] = packF(qv[0], qv[1]); qf[1] = packF(qv[2], qv[3]);

  float swl = 0.f;
  f32x4 accw[4];
  #pragma unroll
  for (int m = 0; m < 4; ++m) accw[m] = (f32x4)(0.f);

  // initial gather: tiles 0..2 (packed to bf16 immediately)
  Frag nb0[3][2]; int ir[3];
  #pragma unroll
  for (int c = 0; c < 3; ++c){
    const int k = 16*c + r16;
    const int iu = hu[k]; ir[c] = hrw[k];
    const f32x4* ua = (const f32x4*)(u2e + (size_t)iu * 64);
    nb0[c][0] = packF(ua[g], ua[4+g]);
    nb0[c][1] = packF(ua[8+g], ua[12+g]);
  }

  body<3,3>(0, 3,  wl, bl, rbase, hu, hrw, u2e, r16, g, qf, qv, nb0, ir, accw, swl);
  body<3,3>(3, 6,  wl, bl, rbase, hu, hrw, u2e, r16, g, qf, qv, nb0, ir, accw, swl);
  body<3,3>(6, 9,  wl, bl, rbase, hu, hrw, u2e, r16, g, qf, qv, nb0, ir, accw, swl);
  body<3,1>(9, 12, wl, bl, rbase, hu, hrw, u2e, r16, g, qf, qv, nb0, ir, accw, swl);
  body<1,0>(12, 0, wl, bl, rbase, hu, hrw, u2e, r16, g, qf, qv, nb0, ir, accw, swl);

  // finale: reduce over the 16 row-lanes (accw and swl), scale, store
  #pragma unroll
  for (int o = 1; o < 16; o <<= 1){
    #pragma unroll
    for (int m = 0; m < 4; ++m)
      #pragma unroll
      for (int j = 0; j < 4; ++j)
        accw[m][j] += __shfl_xor(accw[m][j], o);
    swl += __shfl_xor(swl, o);
  }
  if (r16 == 0){
    const float inv = 1.f / swl;
    #pragma unroll
    for (int m = 0; m < 4; ++m){
      f32x4 v = accw[m];
      #pragma unroll
      for (int j = 0; j < 4; ++j) v[j] *= inv;
      *(f32x4*)(out + (size_t)n * 64 + 16*m + 4*g) = v;
    }
  }
}

extern "C" void kernel_launch(void* const* d_in, const int* in_sizes, int n_in,
                              void* d_out, int out_size, void* d_ws, size_t ws_size,
                              hipStream_t stream){
  const int*   nodes = (const int*)  d_in[0];
  const int*   huv   = (const int*)  d_in[1];
  const int*   hr    = (const int*)  d_in[2];
  const float* u2e   = (const float*)d_in[3];
  const float* v2e   = (const float*)d_in[4];
  const float* r2e   = (const float*)d_in[5];
  const float* w1    = (const float*)d_in[6];
  const float* b1    = (const float*)d_in[7];
  const float* w2    = (const float*)d_in[8];
  const float* b2    = (const float*)d_in[9];
  const float* muw   = (const float*)d_in[10];
  const float* mub   = (const float*)d_in[11];
  const float* a1w   = (const float*)d_in[12];
  const float* a1b   = (const float*)d_in[13];
  const float* a2w   = (const float*)d_in[14];
  const float* a2b   = (const float*)d_in[15];
  const float* a3w   = (const float*)d_in[16];
  // d_in[17] = att3_b: constant logit offset -> cancels in softmax.

  const int N = in_sizes[0];            // 2048
  uint4* ws = (uint4*)d_ws;             // 74 KiB: frag table + r2e frags

  hipLaunchKernelGGL(prep_weights, dim3(74), dim3(64), 0, stream,
                     w1, w2, muw, a1w, a2w, r2e, ws);
  hipLaunchKernelGGL(uv_agg_main, dim3(N / 4), dim3(256), 77312, stream,
                     nodes, huv, hr, u2e, v2e,
                     b1, b2, mub, a1b, a2b, a3w,
                     (const uint4*)ws, (float*)d_out);
}

// Round 13
// 73.871 us; speedup vs baseline: 1.9786x; 1.0796x over previous
//
#include <hip/hip_runtime.h>
#include <hip/hip_bf16.h>

typedef float f32x4 __attribute__((ext_vector_type(4)));
typedef __bf16 bf16x8 __attribute__((ext_vector_type(8)));

union Frag { unsigned short h[8]; unsigned int u[4]; uint4 u4; bf16x8 b; };

__device__ __forceinline__ unsigned short f2bs(float f){
  __hip_bfloat16 v = __float2bfloat16(f);
  return __builtin_bit_cast(unsigned short, v);
}
// 1-instruction bf16 pair pack (RNE)
__device__ __forceinline__ unsigned int pk2(float a, float b){
  unsigned int r;
  asm("v_cvt_pk_bf16_f32 %0, %1, %2" : "=v"(r) : "v"(a), "v"(b));
  return r;
}
__device__ __forceinline__ Frag packF(f32x4 a, f32x4 b){
  Frag f;
  f.u[0] = pk2(a[0], a[1]); f.u[1] = pk2(a[2], a[3]);
  f.u[2] = pk2(b[0], b[1]); f.u[3] = pk2(b[2], b[3]);
  return f;
}
// unpack element (m,j) of a packF'd pair-frag back to f32 (exact)
__device__ __forceinline__ float unpk(const Frag& f, int m, int j){
  const unsigned int u = f.u[(m & 1)*2 + (j >> 1)];
  return __builtin_bit_cast(float, (j & 1) ? (u & 0xffff0000u) : (u << 16));
}
__device__ __forceinline__ f32x4 relu4(f32x4 v){
  f32x4 r;
  #pragma unroll
  for (int j = 0; j < 4; ++j) r[j] = fmaxf(v[j], 0.f);
  return r;
}
__device__ __forceinline__ float sigmoid_fast(float x){
  return __builtin_amdgcn_rcpf(1.f + __expf(-x));
}

// ---------------------------------------------------------------------------
// Prep: weight matrices -> MFMA A-frag order bf16 (ws[0..4095] uint4), plus
// r2e's 5 rows pre-packed as B-frag pairs (ws[4096..4735]).
// A-frag element (h,j): W[16*m + (lane&15)][32*s + 16*h + 4*(lane>>4) + j]
// ---------------------------------------------------------------------------
__global__ void prep_weights(const float* __restrict__ w1, const float* __restrict__ w2,
                             const float* __restrict__ mu, const float* __restrict__ a1,
                             const float* __restrict__ a2, const float* __restrict__ r2e,
                             uint4* __restrict__ ws){
  const int f = blockIdx.x;
  const int l = threadIdx.x;
  Frag fr;
  if (f < 64){
    const float* W; int m, s, K;
    if (f < 16)      { W = w1; m = f >> 2;        s = f & 3;        K = 128; }
    else if (f < 24) { W = w2; m = (f - 16) >> 1; s = (f - 16) & 1; K = 64;  }
    else if (f < 40) { W = mu; m = (f - 24) >> 2; s = (f - 24) & 3; K = 128; }
    else if (f < 56) { W = a1; m = (f - 40) >> 2; s = (f - 40) & 3; K = 128; }
    else             { W = a2; m = (f - 56) >> 1; s = (f - 56) & 1; K = 64;  }
    const int row = 16 * m + (l & 15);
    const int k0  = 32 * s + 4 * (l >> 4);
    #pragma unroll
    for (int h = 0; h < 2; ++h)
      #pragma unroll
      for (int j = 0; j < 4; ++j)
        fr.h[4*h + j] = f2bs(W[row * K + k0 + 16*h + j]);
    ws[f * 64 + l] = fr.u4;
  } else {
    const int f2 = f - 64;            // 0..9
    const int R = f2 >> 1, sp = f2 & 1;
    const int g = (l >> 4) & 3;
    #pragma unroll
    for (int h = 0; h < 2; ++h)
      #pragma unroll
      for (int j = 0; j < 4; ++j)
        fr.h[4*h + j] = f2bs(r2e[R * 64 + sp * 32 + 16*h + 4*g + j]);
    ws[4096 + f2 * 64 + l] = fr.u4;
  }
}

// ---------------------------------------------------------------------------
// TRI-CHUNK body, register-dieted (r12 content, unchanged):
//  - S1 consumes nb0/ir DIRECTLY; gather-prefetch issues after S1 (S2..S5
//    ~10K cy covers the ~500cy gather) -> no b0/irc shadow copies.
//  - O dies at end of S2: S3's gate mix unpacks O from the packed bo bf16
//    frags (packed-OG pattern, r10-verified numerics).
// r10: weight frags in regs -> 117MB spill. r11: tri-chunk w/o diet -> 18MB
// spill. Canary: WRITE_SIZE must stay ~0.5MB.
// ---------------------------------------------------------------------------
template<int NC, int NN>
__device__ __forceinline__ void body(
    int tb, int tnb,
    const uint4* wl, const f32x4* bl, const unsigned char* rbase,
    const int* hu, const int* hrw, const float* u2e,
    int r16, int g,
    const Frag (&qf)[2], const f32x4 (&qv)[4],
    Frag (&nb0)[3][2], int (&ir)[3],
    f32x4 (&accw)[4], float& swl)
{
  bool v[3];
  #pragma unroll
  for (int c = 0; c < NC; ++c) v[c] = (16*(tb + c) + r16) < 200;

  // S1: X = relu(W1 @ concat(e_uv, e_r) + b1)   [reads nb0/ir directly]
  f32x4 X[3][4];
  #pragma unroll
  for (int m = 0; m < 4; ++m){
    const f32x4 bi = bl[0*16 + 4*m];
    f32x4 a[3];
    #pragma unroll
    for (int c = 0; c < NC; ++c) a[c] = bi;
    #pragma unroll
    for (int s = 0; s < 4; ++s){
      Frag w; w.u4 = wl[(m*4 + s) * 64];
      #pragma unroll
      for (int c = 0; c < NC; ++c){
        Frag e;
        if (s < 2) e = nb0[c][s];
        else e.u4 = *(const uint4*)(rbase + (size_t)(ir[c]*2 + (s-2)) * 1024);
        a[c] = __builtin_amdgcn_mfma_f32_16x16x32_bf16(w.b, e.b, a[c], 0, 0, 0);
      }
    }
    #pragma unroll
    for (int c = 0; c < NC; ++c) X[c][m] = relu4(a[c]);
  }
  Frag bx[3][2];
  #pragma unroll
  for (int c = 0; c < NC; ++c){
    bx[c][0] = packF(X[c][0], X[c][1]);
    bx[c][1] = packF(X[c][2], X[c][3]);
  }

  // gather-prefetch next NN tiles into nb0/ir (S2..S5 covers the latency)
  #pragma unroll
  for (int c = 0; c < NN; ++c){
    const int k = min(16*(tnb + c) + r16, 199);
    const int iu = hu[k]; ir[c] = hrw[k];
    const f32x4* ua = (const f32x4*)(u2e + (size_t)iu * 64);
    nb0[c][0] = packF(ua[g], ua[4+g]);
    nb0[c][1] = packF(ua[8+g], ua[12+g]);
  }

  // S2: O = relu(W2 @ X + b2); O lives on only as packed bo
  Frag bo[3][2];
  {
    f32x4 Ot[3][4];
    #pragma unroll
    for (int m = 0; m < 4; ++m){
      const f32x4 bi = bl[1*16 + 4*m];
      f32x4 a[3];
      #pragma unroll
      for (int c = 0; c < NC; ++c) a[c] = bi;
      #pragma unroll
      for (int s = 0; s < 2; ++s){
        Frag w; w.u4 = wl[(16 + m*2 + s) * 64];
        #pragma unroll
        for (int c = 0; c < NC; ++c)
          a[c] = __builtin_amdgcn_mfma_f32_16x16x32_bf16(w.b, bx[c][s].b, a[c], 0, 0, 0);
      }
      #pragma unroll
      for (int c = 0; c < NC; ++c) Ot[c][m] = relu4(a[c]);
    }
    #pragma unroll
    for (int c = 0; c < NC; ++c){
      bo[c][0] = packF(Ot[c][0], Ot[c][1]);
      bo[c][1] = packF(Ot[c][2], Ot[c][3]);
    }
  }

  // S3: gate = sigmoid(MU @ concat(O,q) + mu_b); OG = q + gate*(O-q)
  // O unpacked from bo (bf16-rounded, same values S3's MFMA consumed)
  Frag bg[3][2];
  #pragma unroll
  for (int m = 0; m < 4; ++m){
    const f32x4 bi = bl[2*16 + 4*m];
    f32x4 a[3];
    #pragma unroll
    for (int c = 0; c < NC; ++c) a[c] = bi;
    #pragma unroll
    for (int s = 0; s < 4; ++s){
      Frag w; w.u4 = wl[(24 + m*4 + s) * 64];
      #pragma unroll
      for (int c = 0; c < NC; ++c){
        const bf16x8 e = (s < 2) ? bo[c][s].b : qf[s-2].b;
        a[c] = __builtin_amdgcn_mfma_f32_16x16x32_bf16(w.b, e, a[c], 0, 0, 0);
      }
    }
    #pragma unroll
    for (int c = 0; c < NC; ++c){
      f32x4 og;
      #pragma unroll
      for (int j = 0; j < 4; ++j){
        const float Ob = unpk(bo[c][m >> 1], m, j);
        const float gg = sigmoid_fast(a[c][j]);
        og[j] = fmaf(gg, Ob - qv[m][j], qv[m][j]);
      }
      bg[c][m >> 1].u[(m & 1)*2 + 0] = pk2(og[0], og[1]);
      bg[c][m >> 1].u[(m & 1)*2 + 1] = pk2(og[2], og[3]);
    }
  }

  // S4: A1 = relu(ATT1 @ concat(OG,q) + att1_b)
  f32x4 A1[3][4];
  #pragma unroll
  for (int m = 0; m < 4; ++m){
    const f32x4 bi = bl[3*16 + 4*m];
    f32x4 a[3];
    #pragma unroll
    for (int c = 0; c < NC; ++c) a[c] = bi;
    #pragma unroll
    for (int s = 0; s < 4; ++s){
      Frag w; w.u4 = wl[(40 + m*4 + s) * 64];
      #pragma unroll
      for (int c = 0; c < NC; ++c){
        const bf16x8 e = (s < 2) ? bg[c][s].b : qf[s-2].b;
        a[c] = __builtin_amdgcn_mfma_f32_16x16x32_bf16(w.b, e, a[c], 0, 0, 0);
      }
    }
    #pragma unroll
    for (int c = 0; c < NC; ++c) A1[c][m] = relu4(a[c]);
  }
  Frag b4[3][2];
  #pragma unroll
  for (int c = 0; c < NC; ++c){
    b4[c][0] = packF(A1[c][0], A1[c][1]);
    b4[c][1] = packF(A1[c][2], A1[c][3]);
  }

  // S5: A2 = relu(ATT2 @ A1 + att2_b); logit = dot(att3_w, A2_row)
  float p[3] = {0.f, 0.f, 0.f};
  #pragma unroll
  for (int m = 0; m < 4; ++m){
    const f32x4 bi = bl[4*16 + 4*m];
    f32x4 a[3];
    #pragma unroll
    for (int c = 0; c < NC; ++c) a[c] = bi;
    #pragma unroll
    for (int s = 0; s < 2; ++s){
      Frag w; w.u4 = wl[(56 + m*2 + s) * 64];
      #pragma unroll
      for (int c = 0; c < NC; ++c)
        a[c] = __builtin_amdgcn_mfma_f32_16x16x32_bf16(w.b, b4[c][s].b, a[c], 0, 0, 0);
    }
    const f32x4 a3m = bl[5*16 + 4*m];
    #pragma unroll
    for (int c = 0; c < NC; ++c){
      const f32x4 r = relu4(a[c]);
      #pragma unroll
      for (int j = 0; j < 4; ++j) p[c] = fmaf(a3m[j], r[j], p[c]);
    }
  }
  float e[3];
  #pragma unroll
  for (int c = 0; c < NC; ++c){
    p[c] += __shfl_xor(p[c], 16);
    p[c] += __shfl_xor(p[c], 32);
    // max-free online softmax (logits O(1e-2); guard 60); es-reduce deferred
    e[c] = v[c] ? __expf(fminf(p[c], 60.f)) : 0.f;
    swl += e[c];
  }
  // accumulate OG from packed bf16
  #pragma unroll
  for (int m = 0; m < 4; ++m)
    #pragma unroll
    for (int j = 0; j < 4; ++j){
      float acc = accw[m][j];
      #pragma unroll
      for (int c = 0; c < NC; ++c)
        acc = fmaf(e[c], unpk(bg[c][m >> 1], m, j), acc);
      accw[m][j] = acc;
    }
}

// ---------------------------------------------------------------------------
// Main: grid 512 x 256thr, wave w owns node n = b*4+w end-to-end. Tri-chunk
// (register-dieted): 4 iterations of 3 tiles (0..11) + single tail (12).
// ROUND-13 FIX: bias staging loop restored to the strided form. Round 9
// accidentally changed `for (i = tid; i < 384; i += 256)` to `if (tid < 384)`
// while the block is 256 threads -> bias[256..383] (att2_b, att3_w) were
// NEVER staged; r9/r11 passed on benign stale LDS, r12 hit toxic garbage
// (NaN). Lesson: every tid-guard must be audited against blockDim.
// NOTE: no min-waves launch_bounds (r3: cap=spill).
// LDS (77312 B): [0,65536) uint4 wlds[4096]; [65536,67072) float bias[384];
//                [67072,77312) uint4 rlds[640]
// ---------------------------------------------------------------------------
__global__ __launch_bounds__(256)
void uv_agg_main(const int* __restrict__ nodes, const int* __restrict__ huv,
                 const int* __restrict__ hr, const float* __restrict__ u2e,
                 const float* __restrict__ v2e,
                 const float* __restrict__ b1g, const float* __restrict__ b2g,
                 const float* __restrict__ bmg, const float* __restrict__ ba1g,
                 const float* __restrict__ ba2g, const float* __restrict__ a3g,
                 const uint4* __restrict__ wsfrag, float* __restrict__ out){
  extern __shared__ unsigned char smem[];
  uint4* wlds = (uint4*)smem;
  float* bias = (float*)(smem + 65536);
  uint4* rlds = (uint4*)(smem + 67072);

  const int tid  = threadIdx.x;
  const int lane = tid & 63;
  const int wave = tid >> 6;
  const int g    = lane >> 4;
  const int r16  = lane & 15;
  const int n    = blockIdx.x * 4 + wave;

  // stage weight frag table + r2e frags + biases into LDS
  #pragma unroll 4
  for (int i = tid; i < 4096; i += 256) wlds[i] = wsfrag[i];
  for (int i = tid; i < 640; i += 256)  rlds[i] = wsfrag[4096 + i];
  for (int i = tid; i < 384; i += 256){          // FIXED: full 384 staged
    const int w = i >> 6, d = i & 63;
    const float* src = (w==0)?b1g:(w==1)?b2g:(w==2)?bmg:(w==3)?ba1g:(w==4)?ba2g:a3g;
    bias[i] = src[d];
  }
  __syncthreads();

  const uint4* wl = wlds + lane;
  const f32x4* bl = (const f32x4*)bias + g;
  const unsigned char* rbase = (const unsigned char*)rlds + lane * 16;
  const int* hu  = huv + n * 200;
  const int* hrw = hr  + n * 200;

  // per-node q = v2e[nodes[n]]
  const int item = nodes[n];
  f32x4 qv[4];
  #pragma unroll
  for (int m = 0; m < 4; ++m)
    qv[m] = *(const f32x4*)(v2e + (size_t)item * 64 + 16*m + 4*g);
  Frag qf[2];
  qf[0] = packF(qv[0], qv[1]); qf[1] = packF(qv[2], qv[3]);

  float swl = 0.f;
  f32x4 accw[4];
  #pragma unroll
  for (int m = 0; m < 4; ++m) accw[m] = (f32x4)(0.f);

  // initial gather: tiles 0..2 (packed to bf16 immediately)
  Frag nb0[3][2]; int ir[3];
  #pragma unroll
  for (int c = 0; c < 3; ++c){
    const int k = 16*c + r16;
    const int iu = hu[k]; ir[c] = hrw[k];
    const f32x4* ua = (const f32x4*)(u2e + (size_t)iu * 64);
    nb0[c][0] = packF(ua[g], ua[4+g]);
    nb0[c][1] = packF(ua[8+g], ua[12+g]);
  }

  body<3,3>(0, 3,  wl, bl, rbase, hu, hrw, u2e, r16, g, qf, qv, nb0, ir, accw, swl);
  body<3,3>(3, 6,  wl, bl, rbase, hu, hrw, u2e, r16, g, qf, qv, nb0, ir, accw, swl);
  body<3,3>(6, 9,  wl, bl, rbase, hu, hrw, u2e, r16, g, qf, qv, nb0, ir, accw, swl);
  body<3,1>(9, 12, wl, bl, rbase, hu, hrw, u2e, r16, g, qf, qv, nb0, ir, accw, swl);
  body<1,0>(12, 0, wl, bl, rbase, hu, hrw, u2e, r16, g, qf, qv, nb0, ir, accw, swl);

  // finale: reduce over the 16 row-lanes (accw and swl), scale, store
  #pragma unroll
  for (int o = 1; o < 16; o <<= 1){
    #pragma unroll
    for (int m = 0; m < 4; ++m)
      #pragma unroll
      for (int j = 0; j < 4; ++j)
        accw[m][j] += __shfl_xor(accw[m][j], o);
    swl += __shfl_xor(swl, o);
  }
  if (r16 == 0){
    const float inv = 1.f / swl;
    #pragma unroll
    for (int m = 0; m < 4; ++m){
      f32x4 v = accw[m];
      #pragma unroll
      for (int j = 0; j < 4; ++j) v[j] *= inv;
      *(f32x4*)(out + (size_t)n * 64 + 16*m + 4*g) = v;
    }
  }
}

extern "C" void kernel_launch(void* const* d_in, const int* in_sizes, int n_in,
                              void* d_out, int out_size, void* d_ws, size_t ws_size,
                              hipStream_t stream){
  const int*   nodes = (const int*)  d_in[0];
  const int*   huv   = (const int*)  d_in[1];
  const int*   hr    = (const int*)  d_in[2];
  const float* u2e   = (const float*)d_in[3];
  const float* v2e   = (const float*)d_in[4];
  const float* r2e   = (const float*)d_in[5];
  const float* w1    = (const float*)d_in[6];
  const float* b1    = (const float*)d_in[7];
  const float* w2    = (const float*)d_in[8];
  const float* b2    = (const float*)d_in[9];
  const float* muw   = (const float*)d_in[10];
  const float* mub   = (const float*)d_in[11];
  const float* a1w   = (const float*)d_in[12];
  const float* a1b   = (const float*)d_in[13];
  const float* a2w   = (const float*)d_in[14];
  const float* a2b   = (const float*)d_in[15];
  const float* a3w   = (const float*)d_in[16];
  // d_in[17] = att3_b: constant logit offset -> cancels in softmax.

  const int N = in_sizes[0];            // 2048
  uint4* ws = (uint4*)d_ws;             // 74 KiB: frag table + r2e frags

  hipLaunchKernelGGL(prep_weights, dim3(74), dim3(64), 0, stream,
                     w1, w2, muw, a1w, a2w, r2e, ws);
  hipLaunchKernelGGL(uv_agg_main, dim3(N / 4), dim3(256), 77312, stream,
                     nodes, huv, hr, u2e, v2e,
                     b1, b2, mub, a1b, a2b, a3w,
                     (const uint4*)ws, (float*)d_out);
}

// Round 14
// 53.239 us; speedup vs baseline: 2.7454x; 1.3875x over previous
//
#include <hip/hip_runtime.h>
#include <hip/hip_bf16.h>

typedef float f32x4 __attribute__((ext_vector_type(4)));
typedef __bf16 bf16x8 __attribute__((ext_vector_type(8)));

union Frag { unsigned short h[8]; unsigned int u[4]; uint4 u4; bf16x8 b; };

__device__ __forceinline__ unsigned short f2bs(float f){
  __hip_bfloat16 v = __float2bfloat16(f);
  return __builtin_bit_cast(unsigned short, v);
}
// 1-instruction bf16 pair pack (RNE)
__device__ __forceinline__ unsigned int pk2(float a, float b){
  unsigned int r;
  asm("v_cvt_pk_bf16_f32 %0, %1, %2" : "=v"(r) : "v"(a), "v"(b));
  return r;
}
__device__ __forceinline__ Frag packF(f32x4 a, f32x4 b){
  Frag f;
  f.u[0] = pk2(a[0], a[1]); f.u[1] = pk2(a[2], a[3]);
  f.u[2] = pk2(b[0], b[1]); f.u[3] = pk2(b[2], b[3]);
  return f;
}
__device__ __forceinline__ f32x4 relu4(f32x4 v){
  f32x4 r;
  #pragma unroll
  for (int j = 0; j < 4; ++j) r[j] = fmaxf(v[j], 0.f);
  return r;
}
__device__ __forceinline__ float sigmoid_fast(float x){
  return __builtin_amdgcn_rcpf(1.f + __expf(-x));
}

// ---------------------------------------------------------------------------
// Prep: weight matrices -> MFMA A-frag order bf16 (ws[0..4095] uint4), plus
// r2e's 5 rows pre-packed as B-frag pairs (ws[4096..4735]).
// A-frag element (h,j): W[16*m + (lane&15)][32*s + 16*h + 4*(lane>>4) + j]
// ---------------------------------------------------------------------------
__global__ void prep_weights(const float* __restrict__ w1, const float* __restrict__ w2,
                             const float* __restrict__ mu, const float* __restrict__ a1,
                             const float* __restrict__ a2, const float* __restrict__ r2e,
                             uint4* __restrict__ ws){
  const int f = blockIdx.x;
  const int l = threadIdx.x;
  Frag fr;
  if (f < 64){
    const float* W; int m, s, K;
    if (f < 16)      { W = w1; m = f >> 2;        s = f & 3;        K = 128; }
    else if (f < 24) { W = w2; m = (f - 16) >> 1; s = (f - 16) & 1; K = 64;  }
    else if (f < 40) { W = mu; m = (f - 24) >> 2; s = (f - 24) & 3; K = 128; }
    else if (f < 56) { W = a1; m = (f - 40) >> 2; s = (f - 40) & 3; K = 128; }
    else             { W = a2; m = (f - 56) >> 1; s = (f - 56) & 1; K = 64;  }
    const int row = 16 * m + (l & 15);
    const int k0  = 32 * s + 4 * (l >> 4);
    #pragma unroll
    for (int h = 0; h < 2; ++h)
      #pragma unroll
      for (int j = 0; j < 4; ++j)
        fr.h[4*h + j] = f2bs(W[row * K + k0 + 16*h + j]);
    ws[f * 64 + l] = fr.u4;
  } else {
    const int f2 = f - 64;            // 0..9
    const int R = f2 >> 1, sp = f2 & 1;
    const int g = (l >> 4) & 3;
    #pragma unroll
    for (int h = 0; h < 2; ++h)
      #pragma unroll
      for (int j = 0; j < 4; ++j)
        fr.h[4*h + j] = f2bs(r2e[R * 64 + sp * 32 + 16*h + 4*g + j]);
    ws[4096 + f2 * 64 + l] = fr.u4;
  }
}

// ---------------------------------------------------------------------------
// Main: grid 512 x 256thr, wave w owns node n = b*4+w. DUAL-CHUNK (the
// measured ILP optimum: r13 proved tri-chunk at 252 regs is SLOWER than
// dual at 96 — register pressure serializes the interleave). Exact r6 body
// plus two verified deltas:
//  (1) deferred es-reduce (r13 numerics): no per-iteration ds_swizzle chain;
//      swl accumulates per-lane, reduced once in the finale.
//  (2) s_setprio(1) around each stage's MFMA cluster: waves here are
//      barrier-free and phase-drifted (attn-like regime where setprio paid).
// NOTE: no min-waves launch_bounds arg (r3: cap => ~1GB scratch spill).
// LDS (77312 B): [0,65536) uint4 wlds[4096]; [65536,67072) float bias[384];
//                [67072,77312) uint4 rlds[640]
// ---------------------------------------------------------------------------
__global__ __launch_bounds__(256)
void uv_agg_main(const int* __restrict__ nodes, const int* __restrict__ huv,
                 const int* __restrict__ hr, const float* __restrict__ u2e,
                 const float* __restrict__ v2e,
                 const float* __restrict__ b1g, const float* __restrict__ b2g,
                 const float* __restrict__ bmg, const float* __restrict__ ba1g,
                 const float* __restrict__ ba2g, const float* __restrict__ a3g,
                 const uint4* __restrict__ wsfrag, float* __restrict__ out){
  extern __shared__ unsigned char smem[];
  uint4* wlds = (uint4*)smem;
  float* bias = (float*)(smem + 65536);
  uint4* rlds = (uint4*)(smem + 67072);

  const int tid  = threadIdx.x;
  const int lane = tid & 63;
  const int wave = tid >> 6;
  const int g    = lane >> 4;
  const int r16  = lane & 15;
  const int n    = blockIdx.x * 4 + wave;

  // stage weight frag table + r2e frags + biases into LDS
  #pragma unroll 4
  for (int i = tid; i < 4096; i += 256) wlds[i] = wsfrag[i];
  for (int i = tid; i < 640; i += 256)  rlds[i] = wsfrag[4096 + i];
  for (int i = tid; i < 384; i += 256){
    const int w = i >> 6, d = i & 63;
    const float* src = (w==0)?b1g:(w==1)?b2g:(w==2)?bmg:(w==3)?ba1g:(w==4)?ba2g:a3g;
    bias[i] = src[d];
  }
  __syncthreads();

  const uint4* wl = wlds + lane;
  const f32x4* bl = (const f32x4*)bias + g;
  const unsigned char* rbase = (const unsigned char*)rlds + lane * 16;
  const int* hu  = huv + n * 200;
  const int* hrw = hr  + n * 200;

  // per-node q = v2e[nodes[n]]
  const int item = nodes[n];
  f32x4 qv[4];
  #pragma unroll
  for (int m = 0; m < 4; ++m)
    qv[m] = *(const f32x4*)(v2e + (size_t)item * 64 + 16*m + 4*g);
  Frag qf[2];
  qf[0] = packF(qv[0], qv[1]); qf[1] = packF(qv[2], qv[3]);

  float swl = 0.f;                 // per-lane exp-sum (reduced in finale)
  f32x4 accw[4];
  #pragma unroll
  for (int m = 0; m < 4; ++m) accw[m] = (f32x4)(0.f);

  // initial gather: tiles 0 and 1
  int irA, irB;
  f32x4 urA[4], urB[4];
  {
    const int iuA = hu[r16];      irA = hrw[r16];
    const int iuB = hu[16 + r16]; irB = hrw[16 + r16];
    const f32x4* ua = (const f32x4*)(u2e + (size_t)iuA * 64);
    const f32x4* ub = (const f32x4*)(u2e + (size_t)iuB * 64);
    #pragma unroll
    for (int s = 0; s < 4; ++s){ urA[s] = ua[4*s + g]; urB[s] = ub[4*s + g]; }
  }

  for (int it = 0; it < 7; ++it){
    Frag b0A[2], b0B[2];
    b0A[0] = packF(urA[0], urA[1]); b0A[1] = packF(urA[2], urA[3]);
    b0B[0] = packF(urB[0], urB[1]); b0B[1] = packF(urB[2], urB[3]);
    const int ircA = irA, ircB = irB;
    const bool vA = (it < 6) || (r16 < 8);   // tile 12: rows 192..199
    const bool vB = (it < 6);                // tile 13: none

    // prefetch next pair (independent of this iteration's chains)
    if (it < 6){
      const int base = 32*it + 32;
      const int kA = min(base + r16, 199);
      const int kB = min(base + 16 + r16, 199);
      const int iuA = hu[kA]; irA = hrw[kA];
      const int iuB = hu[kB]; irB = hrw[kB];
      const f32x4* ua = (const f32x4*)(u2e + (size_t)iuA * 64);
      const f32x4* ub = (const f32x4*)(u2e + (size_t)iuB * 64);
      #pragma unroll
      for (int s = 0; s < 4; ++s){ urA[s] = ua[4*s + g]; urB[s] = ub[4*s + g]; }
    }

    // S1: X = relu(W1 @ concat(e_uv, e_r) + b1)   [two chunks interleaved]
    f32x4 XA[4], XB[4];
    __builtin_amdgcn_s_setprio(1);
    #pragma unroll
    for (int m = 0; m < 4; ++m){
      const f32x4 bi = bl[0*16 + 4*m];
      f32x4 aA = bi, aB = bi;
      #pragma unroll
      for (int s = 0; s < 4; ++s){
        Frag w; w.u4 = wl[(m*4 + s) * 64];
        Frag eA, eB;
        if (s < 2){ eA = b0A[s]; eB = b0B[s]; }
        else {
          eA.u4 = *(const uint4*)(rbase + (size_t)(ircA*2 + (s-2)) * 1024);
          eB.u4 = *(const uint4*)(rbase + (size_t)(ircB*2 + (s-2)) * 1024);
        }
        aA = __builtin_amdgcn_mfma_f32_16x16x32_bf16(w.b, eA.b, aA, 0, 0, 0);
        aB = __builtin_amdgcn_mfma_f32_16x16x32_bf16(w.b, eB.b, aB, 0, 0, 0);
      }
      XA[m] = relu4(aA); XB[m] = relu4(aB);
    }
    __builtin_amdgcn_s_setprio(0);
    Frag bxA[2], bxB[2];
    bxA[0] = packF(XA[0], XA[1]); bxA[1] = packF(XA[2], XA[3]);
    bxB[0] = packF(XB[0], XB[1]); bxB[1] = packF(XB[2], XB[3]);

    // S2: O = relu(W2 @ X + b2)
    f32x4 OA[4], OB[4];
    __builtin_amdgcn_s_setprio(1);
    #pragma unroll
    for (int m = 0; m < 4; ++m){
      const f32x4 bi = bl[1*16 + 4*m];
      f32x4 aA = bi, aB = bi;
      #pragma unroll
      for (int s = 0; s < 2; ++s){
        Frag w; w.u4 = wl[(16 + m*2 + s) * 64];
        aA = __builtin_amdgcn_mfma_f32_16x16x32_bf16(w.b, bxA[s].b, aA, 0, 0, 0);
        aB = __builtin_amdgcn_mfma_f32_16x16x32_bf16(w.b, bxB[s].b, aB, 0, 0, 0);
      }
      OA[m] = relu4(aA); OB[m] = relu4(aB);
    }
    __builtin_amdgcn_s_setprio(0);
    Frag boA[2], boB[2];
    boA[0] = packF(OA[0], OA[1]); boA[1] = packF(OA[2], OA[3]);
    boB[0] = packF(OB[0], OB[1]); boB[1] = packF(OB[2], OB[3]);

    // S3: gate = sigmoid(MU @ concat(O,q) + mu_b); OG = q + gate*(O-q)
    f32x4 OGA[4], OGB[4];
    __builtin_amdgcn_s_setprio(1);
    #pragma unroll
    for (int m = 0; m < 4; ++m){
      const f32x4 bi = bl[2*16 + 4*m];
      f32x4 aA = bi, aB = bi;
      #pragma unroll
      for (int s = 0; s < 4; ++s){
        Frag w; w.u4 = wl[(24 + m*4 + s) * 64];
        const bf16x8 eA = (s < 2) ? boA[s].b : qf[s-2].b;
        const bf16x8 eB = (s < 2) ? boB[s].b : qf[s-2].b;
        aA = __builtin_amdgcn_mfma_f32_16x16x32_bf16(w.b, eA, aA, 0, 0, 0);
        aB = __builtin_amdgcn_mfma_f32_16x16x32_bf16(w.b, eB, aB, 0, 0, 0);
      }
      #pragma unroll
      for (int j = 0; j < 4; ++j){
        const float gA = sigmoid_fast(aA[j]);
        const float gB = sigmoid_fast(aB[j]);
        OGA[m][j] = fmaf(gA, OA[m][j] - qv[m][j], qv[m][j]);
        OGB[m][j] = fmaf(gB, OB[m][j] - qv[m][j], qv[m][j]);
      }
    }
    __builtin_amdgcn_s_setprio(0);
    Frag bgA[2], bgB[2];
    bgA[0] = packF(OGA[0], OGA[1]); bgA[1] = packF(OGA[2], OGA[3]);
    bgB[0] = packF(OGB[0], OGB[1]); bgB[1] = packF(OGB[2], OGB[3]);

    // S4: A1 = relu(ATT1 @ concat(OG,q) + att1_b)
    f32x4 A1A[4], A1B[4];
    __builtin_amdgcn_s_setprio(1);
    #pragma unroll
    for (int m = 0; m < 4; ++m){
      const f32x4 bi = bl[3*16 + 4*m];
      f32x4 aA = bi, aB = bi;
      #pragma unroll
      for (int s = 0; s < 4; ++s){
        Frag w; w.u4 = wl[(40 + m*4 + s) * 64];
        const bf16x8 eA = (s < 2) ? bgA[s].b : qf[s-2].b;
        const bf16x8 eB = (s < 2) ? bgB[s].b : qf[s-2].b;
        aA = __builtin_amdgcn_mfma_f32_16x16x32_bf16(w.b, eA, aA, 0, 0, 0);
        aB = __builtin_amdgcn_mfma_f32_16x16x32_bf16(w.b, eB, aB, 0, 0, 0);
      }
      A1A[m] = relu4(aA); A1B[m] = relu4(aB);
    }
    __builtin_amdgcn_s_setprio(0);
    Frag b4A[2], b4B[2];
    b4A[0] = packF(A1A[0], A1A[1]); b4A[1] = packF(A1A[2], A1A[3]);
    b4B[0] = packF(A1B[0], A1B[1]); b4B[1] = packF(A1B[2], A1B[3]);

    // S5: A2 = relu(ATT2 @ A1 + att2_b); logit = dot(att3_w, A2_row)
    float pA = 0.f, pB = 0.f;
    __builtin_amdgcn_s_setprio(1);
    #pragma unroll
    for (int m = 0; m < 4; ++m){
      const f32x4 bi = bl[4*16 + 4*m];
      f32x4 aA = bi, aB = bi;
      #pragma unroll
      for (int s = 0; s < 2; ++s){
        Frag w; w.u4 = wl[(56 + m*2 + s) * 64];
        aA = __builtin_amdgcn_mfma_f32_16x16x32_bf16(w.b, b4A[s].b, aA, 0, 0, 0);
        aB = __builtin_amdgcn_mfma_f32_16x16x32_bf16(w.b, b4B[s].b, aB, 0, 0, 0);
      }
      aA = relu4(aA); aB = relu4(aB);
      const f32x4 a3m = bl[5*16 + 4*m];
      #pragma unroll
      for (int j = 0; j < 4; ++j){
        pA = fmaf(a3m[j], aA[j], pA);
        pB = fmaf(a3m[j], aB[j], pB);
      }
    }
    __builtin_amdgcn_s_setprio(0);
    pA += __shfl_xor(pA, 16); pA += __shfl_xor(pA, 32);
    pB += __shfl_xor(pB, 16); pB += __shfl_xor(pB, 32);

    // max-free online softmax (logits O(1e-2); guard at 60); es-reduce deferred
    const float eA = vA ? __expf(fminf(pA, 60.f)) : 0.f;
    const float eB = vB ? __expf(fminf(pB, 60.f)) : 0.f;
    swl += eA + eB;
    #pragma unroll
    for (int m = 0; m < 4; ++m)
      #pragma unroll
      for (int j = 0; j < 4; ++j)
        accw[m][j] = fmaf(eA, OGA[m][j], fmaf(eB, OGB[m][j], accw[m][j]));
  }

  // finale: reduce over the 16 row-lanes (accw and swl), scale, store
  #pragma unroll
  for (int o = 1; o < 16; o <<= 1){
    #pragma unroll
    for (int m = 0; m < 4; ++m)
      #pragma unroll
      for (int j = 0; j < 4; ++j)
        accw[m][j] += __shfl_xor(accw[m][j], o);
    swl += __shfl_xor(swl, o);
  }
  if (r16 == 0){
    const float inv = 1.f / swl;
    #pragma unroll
    for (int m = 0; m < 4; ++m){
      f32x4 v = accw[m];
      #pragma unroll
      for (int j = 0; j < 4; ++j) v[j] *= inv;
      *(f32x4*)(out + (size_t)n * 64 + 16*m + 4*g) = v;
    }
  }
}

extern "C" void kernel_launch(void* const* d_in, const int* in_sizes, int n_in,
                              void* d_out, int out_size, void* d_ws, size_t ws_size,
                              hipStream_t stream){
  const int*   nodes = (const int*)  d_in[0];
  const int*   huv   = (const int*)  d_in[1];
  const int*   hr    = (const int*)  d_in[2];
  const float* u2e   = (const float*)d_in[3];
  const float* v2e   = (const float*)d_in[4];
  const float* r2e   = (const float*)d_in[5];
  const float* w1    = (const float*)d_in[6];
  const float* b1    = (const float*)d_in[7];
  const float* w2    = (const float*)d_in[8];
  const float* b2    = (const float*)d_in[9];
  const float* muw   = (const float*)d_in[10];
  const float* mub   = (const float*)d_in[11];
  const float* a1w   = (const float*)d_in[12];
  const float* a1b   = (const float*)d_in[13];
  const float* a2w   = (const float*)d_in[14];
  const float* a2b   = (const float*)d_in[15];
  const float* a3w   = (const float*)d_in[16];
  // d_in[17] = att3_b: constant logit offset -> cancels in softmax.

  const int N = in_sizes[0];            // 2048
  uint4* ws = (uint4*)d_ws;             // 74 KiB: frag table + r2e frags

  hipLaunchKernelGGL(prep_weights, dim3(74), dim3(64), 0, stream,
                     w1, w2, muw, a1w, a2w, r2e, ws);
  hipLaunchKernelGGL(uv_agg_main, dim3(N / 4), dim3(256), 77312, stream,
                     nodes, huv, hr, u2e, v2e,
                     b1, b2, mub, a1b, a2b, a3w,
                     (const uint4*)ws, (float*)d_out);
}

// Round 15
// 47.260 us; speedup vs baseline: 3.0927x; 1.1265x over previous
//
#include <hip/hip_runtime.h>
#include <hip/hip_bf16.h>

typedef float f32x4 __attribute__((ext_vector_type(4)));
typedef __bf16 bf16x8 __attribute__((ext_vector_type(8)));

union Frag { unsigned short h[8]; unsigned int u[4]; uint4 u4; bf16x8 b; };

__device__ __forceinline__ unsigned short f2bs(float f){
  __hip_bfloat16 v = __float2bfloat16(f);
  return __builtin_bit_cast(unsigned short, v);
}
// 1-instruction bf16 pair pack (RNE)
__device__ __forceinline__ unsigned int pk2(float a, float b){
  unsigned int r;
  asm("v_cvt_pk_bf16_f32 %0, %1, %2" : "=v"(r) : "v"(a), "v"(b));
  return r;
}
__device__ __forceinline__ Frag packF(f32x4 a, f32x4 b){
  Frag f;
  f.u[0] = pk2(a[0], a[1]); f.u[1] = pk2(a[2], a[3]);
  f.u[2] = pk2(b[0], b[1]); f.u[3] = pk2(b[2], b[3]);
  return f;
}
__device__ __forceinline__ f32x4 relu4(f32x4 v){
  f32x4 r;
  #pragma unroll
  for (int j = 0; j < 4; ++j) r[j] = fmaxf(v[j], 0.f);
  return r;
}
__device__ __forceinline__ float sigmoid_fast(float x){
  return __builtin_amdgcn_rcpf(1.f + __expf(-x));
}

// ---------------------------------------------------------------------------
// Prep: weight matrices -> MFMA A-frag order bf16 (ws[0..4095] uint4), r2e
// B-frags (ws[4096..4735], now unused by main but kept), and NEW (r15):
// r1c[5][68] f32 at ws float offset 4736*4: r1c[R][d] = b1[d] +
// sum_k W1[d][64+k]*r2e[R][k] — the S1 e_r-half GEMM has only 5 possible
// results (NUM_R=5), precomputed exactly in fp32.
// ---------------------------------------------------------------------------
__global__ void prep_weights(const float* __restrict__ w1, const float* __restrict__ w2,
                             const float* __restrict__ mu, const float* __restrict__ a1,
                             const float* __restrict__ a2, const float* __restrict__ r2e,
                             const float* __restrict__ b1, uint4* __restrict__ ws){
  const int f = blockIdx.x;
  const int l = threadIdx.x;
  Frag fr;
  if (f < 64){
    const float* W; int m, s, K;
    if (f < 16)      { W = w1; m = f >> 2;        s = f & 3;        K = 128; }
    else if (f < 24) { W = w2; m = (f - 16) >> 1; s = (f - 16) & 1; K = 64;  }
    else if (f < 40) { W = mu; m = (f - 24) >> 2; s = (f - 24) & 3; K = 128; }
    else if (f < 56) { W = a1; m = (f - 40) >> 2; s = (f - 40) & 3; K = 128; }
    else             { W = a2; m = (f - 56) >> 1; s = (f - 56) & 1; K = 64;  }
    const int row = 16 * m + (l & 15);
    const int k0  = 32 * s + 4 * (l >> 4);
    #pragma unroll
    for (int h = 0; h < 2; ++h)
      #pragma unroll
      for (int j = 0; j < 4; ++j)
        fr.h[4*h + j] = f2bs(W[row * K + k0 + 16*h + j]);
    ws[f * 64 + l] = fr.u4;
  } else if (f < 74){
    const int f2 = f - 64;            // 0..9
    const int R = f2 >> 1, sp = f2 & 1;
    const int g = (l >> 4) & 3;
    #pragma unroll
    for (int h = 0; h < 2; ++h)
      #pragma unroll
      for (int j = 0; j < 4; ++j)
        fr.h[4*h + j] = f2bs(r2e[R * 64 + sp * 32 + 16*h + 4*g + j]);
    ws[4096 + f2 * 64 + l] = fr.u4;
  } else {
    // r1c table: thread l = output dim d
    float* r1c = (float*)(ws + 4736);
    const int d = l;
    for (int R = 0; R < 5; ++R){
      float s = b1[d];
      for (int k = 0; k < 64; ++k)
        s = fmaf(w1[d * 128 + 64 + k], r2e[R * 64 + k], s);
      r1c[R * 68 + d] = s;     // stride 68 floats (bank-spread)
    }
  }
}

// ---------------------------------------------------------------------------
// Main: grid 512 x 256thr, wave w owns node n = b*4+w. DUAL-CHUNK (measured
// ILP optimum, r13). ROUND-15: loop-invariant GEMM halves hoisted out of the
// iteration — S1's e_r half is a 5-entry precomputed table (r1c, LDS read as
// acc-init), S3/S4's q halves are computed ONCE per wave into muq/a1q regs.
// MFMAs per iteration: 128 -> 80; dependent-MFMA chain per acc halves in
// S1/S3/S4. r2e frag table no longer staged (LDS 77312 -> 68432 B).
// NOTE: no min-waves launch_bounds arg (r3: cap => ~1GB scratch spill).
// LDS (68432 B): [0,65536) uint4 wlds[4096]; [65536,67072) float bias[384];
//                [67072,68432) float r1cl[5*68]
// ---------------------------------------------------------------------------
__global__ __launch_bounds__(256)
void uv_agg_main(const int* __restrict__ nodes, const int* __restrict__ huv,
                 const int* __restrict__ hr, const float* __restrict__ u2e,
                 const float* __restrict__ v2e,
                 const float* __restrict__ b1g, const float* __restrict__ b2g,
                 const float* __restrict__ bmg, const float* __restrict__ ba1g,
                 const float* __restrict__ ba2g, const float* __restrict__ a3g,
                 const uint4* __restrict__ wsfrag, float* __restrict__ out){
  extern __shared__ unsigned char smem[];
  uint4* wlds = (uint4*)smem;
  float* bias = (float*)(smem + 65536);
  float* r1cl = (float*)(smem + 67072);

  const int tid  = threadIdx.x;
  const int lane = tid & 63;
  const int wave = tid >> 6;
  const int g    = lane >> 4;
  const int r16  = lane & 15;
  const int n    = blockIdx.x * 4 + wave;

  // stage weight frag table + biases + r1c into LDS
  #pragma unroll 4
  for (int i = tid; i < 4096; i += 256) wlds[i] = wsfrag[i];
  for (int i = tid; i < 384; i += 256){
    const int w = i >> 6, d = i & 63;
    const float* src = (w==0)?b1g:(w==1)?b2g:(w==2)?bmg:(w==3)?ba1g:(w==4)?ba2g:a3g;
    bias[i] = src[d];
  }
  {
    const float* r1g = (const float*)(wsfrag + 4736);
    for (int i = tid; i < 340; i += 256) r1cl[i] = r1g[i];
  }
  __syncthreads();

  const uint4* wl = wlds + lane;
  const f32x4* bl = (const f32x4*)bias + g;
  const int* hu  = huv + n * 200;
  const int* hrw = hr  + n * 200;

  // per-node q = v2e[nodes[n]]
  const int item = nodes[n];
  f32x4 qv[4];
  #pragma unroll
  for (int m = 0; m < 4; ++m)
    qv[m] = *(const f32x4*)(v2e + (size_t)item * 64 + 16*m + 4*g);
  Frag qf[2];
  qf[0] = packF(qv[0], qv[1]); qf[1] = packF(qv[2], qv[3]);

  // ONE-TIME: muq = mu_b + MU[:,64:]@q ; a1q = att1_b + ATT1[:,64:]@q
  // (B columns all equal q -> every lane/col gets the vector; dead qf after)
  f32x4 muq[4], a1q[4];
  #pragma unroll
  for (int m = 0; m < 4; ++m){
    f32x4 a = bl[2*16 + 4*m];
    {
      Frag w; w.u4 = wl[(24 + m*4 + 2) * 64];
      a = __builtin_amdgcn_mfma_f32_16x16x32_bf16(w.b, qf[0].b, a, 0, 0, 0);
      w.u4 = wl[(24 + m*4 + 3) * 64];
      a = __builtin_amdgcn_mfma_f32_16x16x32_bf16(w.b, qf[1].b, a, 0, 0, 0);
    }
    muq[m] = a;
    f32x4 b = bl[3*16 + 4*m];
    {
      Frag w; w.u4 = wl[(40 + m*4 + 2) * 64];
      b = __builtin_amdgcn_mfma_f32_16x16x32_bf16(w.b, qf[0].b, b, 0, 0, 0);
      w.u4 = wl[(40 + m*4 + 3) * 64];
      b = __builtin_amdgcn_mfma_f32_16x16x32_bf16(w.b, qf[1].b, b, 0, 0, 0);
    }
    a1q[m] = b;
  }

  float swl = 0.f;                 // per-lane exp-sum (reduced in finale)
  f32x4 accw[4];
  #pragma unroll
  for (int m = 0; m < 4; ++m) accw[m] = (f32x4)(0.f);

  // initial gather: tiles 0 and 1
  int irA, irB;
  f32x4 urA[4], urB[4];
  {
    const int iuA = hu[r16];      irA = hrw[r16];
    const int iuB = hu[16 + r16]; irB = hrw[16 + r16];
    const f32x4* ua = (const f32x4*)(u2e + (size_t)iuA * 64);
    const f32x4* ub = (const f32x4*)(u2e + (size_t)iuB * 64);
    #pragma unroll
    for (int s = 0; s < 4; ++s){ urA[s] = ua[4*s + g]; urB[s] = ub[4*s + g]; }
  }

  for (int it = 0; it < 7; ++it){
    Frag b0A[2], b0B[2];
    b0A[0] = packF(urA[0], urA[1]); b0A[1] = packF(urA[2], urA[3]);
    b0B[0] = packF(urB[0], urB[1]); b0B[1] = packF(urB[2], urB[3]);
    const int ircA = irA, ircB = irB;
    const bool vA = (it < 6) || (r16 < 8);   // tile 12: rows 192..199
    const bool vB = (it < 6);                // tile 13: none

    // prefetch next pair (independent of this iteration's chains)
    if (it < 6){
      const int base = 32*it + 32;
      const int kA = min(base + r16, 199);
      const int kB = min(base + 16 + r16, 199);
      const int iuA = hu[kA]; irA = hrw[kA];
      const int iuB = hu[kB]; irB = hrw[kB];
      const f32x4* ua = (const f32x4*)(u2e + (size_t)iuA * 64);
      const f32x4* ub = (const f32x4*)(u2e + (size_t)iuB * 64);
      #pragma unroll
      for (int s = 0; s < 4; ++s){ urA[s] = ua[4*s + g]; urB[s] = ub[4*s + g]; }
    }

    // S1: X = relu(W1a @ e_uv + r1c[ir])   [e_r half precomputed]
    f32x4 XA[4], XB[4];
    __builtin_amdgcn_s_setprio(1);
    #pragma unroll
    for (int m = 0; m < 4; ++m){
      f32x4 aA = *(const f32x4*)&r1cl[ircA*68 + 16*m + 4*g];
      f32x4 aB = *(const f32x4*)&r1cl[ircB*68 + 16*m + 4*g];
      #pragma unroll
      for (int s = 0; s < 2; ++s){
        Frag w; w.u4 = wl[(m*4 + s) * 64];
        aA = __builtin_amdgcn_mfma_f32_16x16x32_bf16(w.b, b0A[s].b, aA, 0, 0, 0);
        aB = __builtin_amdgcn_mfma_f32_16x16x32_bf16(w.b, b0B[s].b, aB, 0, 0, 0);
      }
      XA[m] = relu4(aA); XB[m] = relu4(aB);
    }
    __builtin_amdgcn_s_setprio(0);
    Frag bxA[2], bxB[2];
    bxA[0] = packF(XA[0], XA[1]); bxA[1] = packF(XA[2], XA[3]);
    bxB[0] = packF(XB[0], XB[1]); bxB[1] = packF(XB[2], XB[3]);

    // S2: O = relu(W2 @ X + b2)
    f32x4 OA[4], OB[4];
    __builtin_amdgcn_s_setprio(1);
    #pragma unroll
    for (int m = 0; m < 4; ++m){
      const f32x4 bi = bl[1*16 + 4*m];
      f32x4 aA = bi, aB = bi;
      #pragma unroll
      for (int s = 0; s < 2; ++s){
        Frag w; w.u4 = wl[(16 + m*2 + s) * 64];
        aA = __builtin_amdgcn_mfma_f32_16x16x32_bf16(w.b, bxA[s].b, aA, 0, 0, 0);
        aB = __builtin_amdgcn_mfma_f32_16x16x32_bf16(w.b, bxB[s].b, aB, 0, 0, 0);
      }
      OA[m] = relu4(aA); OB[m] = relu4(aB);
    }
    __builtin_amdgcn_s_setprio(0);
    Frag boA[2], boB[2];
    boA[0] = packF(OA[0], OA[1]); boA[1] = packF(OA[2], OA[3]);
    boB[0] = packF(OB[0], OB[1]); boB[1] = packF(OB[2], OB[3]);

    // S3: gate = sigmoid(MU_O @ O + muq); OG = q + gate*(O-q)
    f32x4 OGA[4], OGB[4];
    __builtin_amdgcn_s_setprio(1);
    #pragma unroll
    for (int m = 0; m < 4; ++m){
      f32x4 aA = muq[m], aB = muq[m];
      #pragma unroll
      for (int s = 0; s < 2; ++s){
        Frag w; w.u4 = wl[(24 + m*4 + s) * 64];
        aA = __builtin_amdgcn_mfma_f32_16x16x32_bf16(w.b, boA[s].b, aA, 0, 0, 0);
        aB = __builtin_amdgcn_mfma_f32_16x16x32_bf16(w.b, boB[s].b, aB, 0, 0, 0);
      }
      #pragma unroll
      for (int j = 0; j < 4; ++j){
        const float gA = sigmoid_fast(aA[j]);
        const float gB = sigmoid_fast(aB[j]);
        OGA[m][j] = fmaf(gA, OA[m][j] - qv[m][j], qv[m][j]);
        OGB[m][j] = fmaf(gB, OB[m][j] - qv[m][j], qv[m][j]);
      }
    }
    __builtin_amdgcn_s_setprio(0);
    Frag bgA[2], bgB[2];
    bgA[0] = packF(OGA[0], OGA[1]); bgA[1] = packF(OGA[2], OGA[3]);
    bgB[0] = packF(OGB[0], OGB[1]); bgB[1] = packF(OGB[2], OGB[3]);

    // S4: A1 = relu(ATT1_O @ OG + a1q)
    f32x4 A1A[4], A1B[4];
    __builtin_amdgcn_s_setprio(1);
    #pragma unroll
    for (int m = 0; m < 4; ++m){
      f32x4 aA = a1q[m], aB = a1q[m];
      #pragma unroll
      for (int s = 0; s < 2; ++s){
        Frag w; w.u4 = wl[(40 + m*4 + s) * 64];
        aA = __builtin_amdgcn_mfma_f32_16x16x32_bf16(w.b, bgA[s].b, aA, 0, 0, 0);
        aB = __builtin_amdgcn_mfma_f32_16x16x32_bf16(w.b, bgB[s].b, aB, 0, 0, 0);
      }
      A1A[m] = relu4(aA); A1B[m] = relu4(aB);
    }
    __builtin_amdgcn_s_setprio(0);
    Frag b4A[2], b4B[2];
    b4A[0] = packF(A1A[0], A1A[1]); b4A[1] = packF(A1A[2], A1A[3]);
    b4B[0] = packF(A1B[0], A1B[1]); b4B[1] = packF(A1B[2], A1B[3]);

    // S5: A2 = relu(ATT2 @ A1 + att2_b); logit = dot(att3_w, A2_row)
    float pA = 0.f, pB = 0.f;
    __builtin_amdgcn_s_setprio(1);
    #pragma unroll
    for (int m = 0; m < 4; ++m){
      const f32x4 bi = bl[4*16 + 4*m];
      f32x4 aA = bi, aB = bi;
      #pragma unroll
      for (int s = 0; s < 2; ++s){
        Frag w; w.u4 = wl[(56 + m*2 + s) * 64];
        aA = __builtin_amdgcn_mfma_f32_16x16x32_bf16(w.b, b4A[s].b, aA, 0, 0, 0);
        aB = __builtin_amdgcn_mfma_f32_16x16x32_bf16(w.b, b4B[s].b, aB, 0, 0, 0);
      }
      aA = relu4(aA); aB = relu4(aB);
      const f32x4 a3m = bl[5*16 + 4*m];
      #pragma unroll
      for (int j = 0; j < 4; ++j){
        pA = fmaf(a3m[j], aA[j], pA);
        pB = fmaf(a3m[j], aB[j], pB);
      }
    }
    __builtin_amdgcn_s_setprio(0);
    pA += __shfl_xor(pA, 16); pA += __shfl_xor(pA, 32);
    pB += __shfl_xor(pB, 16); pB += __shfl_xor(pB, 32);

    // max-free online softmax (logits O(1e-2); guard at 60); es-reduce deferred
    const float eA = vA ? __expf(fminf(pA, 60.f)) : 0.f;
    const float eB = vB ? __expf(fminf(pB, 60.f)) : 0.f;
    swl += eA + eB;
    #pragma unroll
    for (int m = 0; m < 4; ++m)
      #pragma unroll
      for (int j = 0; j < 4; ++j)
        accw[m][j] = fmaf(eA, OGA[m][j], fmaf(eB, OGB[m][j], accw[m][j]));
  }

  // finale: reduce over the 16 row-lanes (accw and swl), scale, store
  #pragma unroll
  for (int o = 1; o < 16; o <<= 1){
    #pragma unroll
    for (int m = 0; m < 4; ++m)
      #pragma unroll
      for (int j = 0; j < 4; ++j)
        accw[m][j] += __shfl_xor(accw[m][j], o);
    swl += __shfl_xor(swl, o);
  }
  if (r16 == 0){
    const float inv = 1.f / swl;
    #pragma unroll
    for (int m = 0; m < 4; ++m){
      f32x4 v = accw[m];
      #pragma unroll
      for (int j = 0; j < 4; ++j) v[j] *= inv;
      *(f32x4*)(out + (size_t)n * 64 + 16*m + 4*g) = v;
    }
  }
}

extern "C" void kernel_launch(void* const* d_in, const int* in_sizes, int n_in,
                              void* d_out, int out_size, void* d_ws, size_t ws_size,
                              hipStream_t stream){
  const int*   nodes = (const int*)  d_in[0];
  const int*   huv   = (const int*)  d_in[1];
  const int*   hr    = (const int*)  d_in[2];
  const float* u2e   = (const float*)d_in[3];
  const float* v2e   = (const float*)d_in[4];
  const float* r2e   = (const float*)d_in[5];
  const float* w1    = (const float*)d_in[6];
  const float* b1    = (const float*)d_in[7];
  const float* w2    = (const float*)d_in[8];
  const float* b2    = (const float*)d_in[9];
  const float* muw   = (const float*)d_in[10];
  const float* mub   = (const float*)d_in[11];
  const float* a1w   = (const float*)d_in[12];
  const float* a1b   = (const float*)d_in[13];
  const float* a2w   = (const float*)d_in[14];
  const float* a2b   = (const float*)d_in[15];
  const float* a3w   = (const float*)d_in[16];
  // d_in[17] = att3_b: constant logit offset -> cancels in softmax.

  const int N = in_sizes[0];            // 2048
  uint4* ws = (uint4*)d_ws;             // frag table + r2e frags + r1c (~76KB)

  hipLaunchKernelGGL(prep_weights, dim3(75), dim3(64), 0, stream,
                     w1, w2, muw, a1w, a2w, r2e, b1, ws);
  hipLaunchKernelGGL(uv_agg_main, dim3(N / 4), dim3(256), 68432, stream,
                     nodes, huv, hr, u2e, v2e,
                     b1, b2, mub, a1b, a2b, a3w,
                     (const uint4*)ws, (float*)d_out);
}